// Round 7
// baseline (874.169 us; speedup 1.0000x reference)
//
#include <hip/hip_runtime.h>

#define D 128
#define HD 256
#define BN_EPS 1e-5f

typedef __attribute__((ext_vector_type(8))) short bh8;
typedef __attribute__((ext_vector_type(4))) float f32x4;

__device__ __forceinline__ float4 ldg4(const float* p) {
    return *reinterpret_cast<const float4*>(p);
}
// bf16 RNE via bit ops (no bfloat16 header needed)
__device__ __forceinline__ unsigned short f2bf(float f) {
    union { float f; unsigned int u; } v; v.f = f;
    unsigned int u = v.u;
    return (unsigned short)((u + 0x7fffu + ((u >> 16) & 1u)) >> 16);
}
__device__ __forceinline__ float bf2f(unsigned short h) {
    union { unsigned int u; float f; } v; v.u = ((unsigned int)h) << 16; return v.f;
}

// ---------------------------------------------------------------------------
// K0: AtomEncoder  h[i] = atom_emb1[x[i,0]] + atom_emb2[x[i,1]]  -> d_out
// ---------------------------------------------------------------------------
__global__ __launch_bounds__(256) void k_atom(
    const int* __restrict__ x,
    const float* __restrict__ ae1, const float* __restrict__ ae2,
    float* __restrict__ h, int N)
{
    int idx = blockIdx.x * 256 + threadIdx.x;
    int row = idx >> 5;
    int d   = (idx & 31) * 4;
    if (row >= N) return;
    int i0 = x[row * 2 + 0];
    int i1 = x[row * 2 + 1];
    float4 a = ldg4(ae1 + (size_t)i0 * D + d);
    float4 b = ldg4(ae2 + (size_t)i1 * D + d);
    float4 o = {a.x + b.x, a.y + b.y, a.z + b.z, a.w + b.w};
    *reinterpret_cast<float4*>(h + (size_t)row * D + d) = o;
}

// ---------------------------------------------------------------------------
// CSR build 1: histogram degrees + per-(dst,combo) counts
// ---------------------------------------------------------------------------
__global__ __launch_bounds__(256) void k_hist(
    const int* __restrict__ ei, const int* __restrict__ ea,
    int* __restrict__ rowptr, int* __restrict__ counts, int E)
{
    int e = blockIdx.x * 256 + threadIdx.x;
    if (e >= E) return;
    int dst = ei[E + e];
    atomicAdd(&rowptr[dst + 1], 1);
    int c = ea[2 * e] * 3 + ea[2 * e + 1];
    atomicAdd(&counts[dst * 9 + c], 1);
}

// ---------------------------------------------------------------------------
// CSR build 2a/2b/2c: multi-block prefix sum (scan1 -> scan2 -> scan3)
// ---------------------------------------------------------------------------
__global__ __launch_bounds__(1024) void k_scan1(
    int* __restrict__ rowptr, int* __restrict__ cursor,
    int* __restrict__ bsum, int N)
{
    __shared__ int wsum[16];
    int t = threadIdx.x, lane = t & 63, w = t >> 6;
    int i = blockIdx.x * 1024 + t;
    int v = (i < N) ? rowptr[i + 1] : 0;
    int incl = v;
#pragma unroll
    for (int off = 1; off < 64; off <<= 1) {
        int y = __shfl_up(incl, off);
        if (lane >= off) incl += y;
    }
    if (lane == 63) wsum[w] = incl;
    __syncthreads();
    if (t < 16) {
        int xv = wsum[t];
#pragma unroll
        for (int off = 1; off < 16; off <<= 1) {
            int y = __shfl_up(xv, off);
            if (t >= off) xv += y;
        }
        wsum[t] = xv;
    }
    __syncthreads();
    int woff = w ? wsum[w - 1] : 0;
    int full = woff + incl;
    if (i < N) { rowptr[i + 1] = full; cursor[i] = full - v; }
    if (t == 1023) bsum[blockIdx.x] = full;
}

__global__ __launch_bounds__(64) void k_scan2(
    const int* __restrict__ bsum, int* __restrict__ boff, int nchunks)
{
    int t = threadIdx.x;
    int carry = 0;
    for (int base = 0; base < nchunks; base += 64) {
        int idx = base + t;
        int v = (idx < nchunks) ? bsum[idx] : 0;
        int incl = v;
#pragma unroll
        for (int off = 1; off < 64; off <<= 1) {
            int y = __shfl_up(incl, off);
            if (t >= off) incl += y;
        }
        if (idx < nchunks) boff[idx] = carry + incl - v;
        carry += __shfl(incl, 63);
    }
}

__global__ __launch_bounds__(1024) void k_scan3(
    int* __restrict__ rowptr, int* __restrict__ cursor,
    const int* __restrict__ boff, int N)
{
    int t = threadIdx.x;
    int i = blockIdx.x * 1024 + t;
    int off = boff[blockIdx.x];
    if (i < N) { rowptr[i + 1] += off; cursor[i] += off; }
    if (blockIdx.x == 0 && t == 0) rowptr[0] = 0;
}

// ---------------------------------------------------------------------------
// CSR build 3: fill edge sources in CSR order
// ---------------------------------------------------------------------------
__global__ __launch_bounds__(256) void k_fill(
    const int* __restrict__ ei, int* __restrict__ cursor,
    int* __restrict__ esrc, int E)
{
    int e = blockIdx.x * 256 + threadIdx.x;
    if (e >= E) return;
    int dst = ei[E + e];
    int pos = atomicAdd(&cursor[dst], 1);
    esrc[pos] = ei[e];
}

// ---------------------------------------------------------------------------
// bec precompute: bec[l][c][d], c=0..8 -> be1[c/3]+be2[c%3], c=9 -> self-loop
// ---------------------------------------------------------------------------
__global__ __launch_bounds__(256) void k_bec(
    const float* __restrict__ be1, const float* __restrict__ be2,
    float* __restrict__ bec)
{
    int idx = blockIdx.x * 256 + threadIdx.x;
    if (idx >= 5 * 10 * D) return;
    int d  = idx & (D - 1);
    int lc = idx >> 7;
    int l = lc / 10, c = lc % 10;
    int a0 = (c == 9) ? 6 : (c / 3);
    int a1 = (c == 9) ? 3 : (c % 3);
    bec[idx] = be1[((size_t)l * 7 + a0) * D + d] + be2[((size_t)l * 4 + a1) * D + d];
}

// ---------------------------------------------------------------------------
// Weight pack: split fp32 W into bf16 hi/lo, fragment-ordered for MFMA B.
// W1p frag (l,nt,kk,lane): 16 ushorts = [8 hi][8 lo], element j:
//   k = kk*32 + (lane>>4)*8 + j ; n = nt*16 + (lane&15)
// ---------------------------------------------------------------------------
__global__ __launch_bounds__(256) void k_wconv(
    const float* __restrict__ W1, const float* __restrict__ W2,
    unsigned short* __restrict__ W1p, unsigned short* __restrict__ W2p)
{
    int tid = blockIdx.x * 256 + threadIdx.x;
    if (tid >= 2 * 5 * 4096) return;
    bool isW2 = tid >= 5 * 4096;
    int r  = tid & 4095;
    int l  = (tid % (5 * 4096)) >> 12;
    int lane = r & 63;
    int l15 = lane & 15, l4 = lane >> 4;
    if (!isW2) {
        int nt = r >> 8;
        int kk = (r >> 6) & 3;
        int n = nt * 16 + l15;
        int kbase = kk * 32 + l4 * 8;
        unsigned short* out = W1p + (size_t)tid * 16;
        const float* src = W1 + ((size_t)l * D + kbase) * HD + n;
#pragma unroll
        for (int j = 0; j < 8; ++j) {
            float wv = src[(size_t)j * HD];
            unsigned short hi = f2bf(wv);
            unsigned short lo = f2bf(wv - bf2f(hi));
            out[j] = hi; out[8 + j] = lo;
        }
    } else {
        int nt = r >> 9;
        int kk = (r >> 6) & 7;
        int n = nt * 16 + l15;
        int kbase = kk * 32 + l4 * 8;
        unsigned short* out = W2p + (size_t)(l * 4096 + r) * 16;
        const float* src = W2 + ((size_t)l * HD + kbase) * D + n;
#pragma unroll
        for (int j = 0; j < 8; ++j) {
            float wv = src[(size_t)j * D];
            unsigned short hi = f2bf(wv);
            unsigned short lo = f2bf(wv - bf2f(hi));
            out[j] = hi; out[8 + j] = lo;
        }
    }
}

// ---------------------------------------------------------------------------
// Gather (+ fused BN affine + relu of previous layer), emits bf16 hi/lo agg.
// aggp row layout: 256 ushorts = [128 hi][128 lo].
// ---------------------------------------------------------------------------
template <int AFFINE>
__global__ __launch_bounds__(256) void k_gather(
    const float* __restrict__ hsrc, const int* __restrict__ rowptr,
    const int* __restrict__ esrc, const int* __restrict__ counts,
    const float* __restrict__ bec,          // [10][D] this layer
    const float* __restrict__ ss,           // [256] scale|shift (prev layer)
    unsigned short* __restrict__ aggp, int N)
{
    int g = threadIdx.x >> 5;
    int lane = threadIdx.x & 31;
    int d = lane * 4;
    int node = blockIdx.x * 8 + g;
    if (node >= N) return;

    float4 sc, sh;
    if (AFFINE) { sc = ldg4(ss + d); sh = ldg4(ss + D + d); }

    float4 acc = ldg4(hsrc + (size_t)node * D + d);
    if (AFFINE) {
        acc.x = fmaf(acc.x, sc.x, sh.x); acc.y = fmaf(acc.y, sc.y, sh.y);
        acc.z = fmaf(acc.z, sc.z, sh.z); acc.w = fmaf(acc.w, sc.w, sh.w);
        acc.x = acc.x > 0.f ? acc.x : 0.f; acc.y = acc.y > 0.f ? acc.y : 0.f;
        acc.z = acc.z > 0.f ? acc.z : 0.f; acc.w = acc.w > 0.f ? acc.w : 0.f;
    }
    float4 sl = ldg4(bec + 9 * D + d);
    acc.x += sl.x; acc.y += sl.y; acc.z += sl.z; acc.w += sl.w;

#pragma unroll
    for (int c = 0; c < 9; ++c) {
        float fc = (float)counts[node * 9 + c];
        float4 b = ldg4(bec + c * D + d);
        acc.x = fmaf(fc, b.x, acc.x);
        acc.y = fmaf(fc, b.y, acc.y);
        acc.z = fmaf(fc, b.z, acc.z);
        acc.w = fmaf(fc, b.w, acc.w);
    }

    int beg = rowptr[node], end = rowptr[node + 1];
    int e = beg;
    for (; e + 3 < end; e += 4) {
        int s0 = esrc[e], s1 = esrc[e + 1], s2 = esrc[e + 2], s3 = esrc[e + 3];
        float4 h0 = ldg4(hsrc + (size_t)s0 * D + d);
        float4 h1 = ldg4(hsrc + (size_t)s1 * D + d);
        float4 h2 = ldg4(hsrc + (size_t)s2 * D + d);
        float4 h3 = ldg4(hsrc + (size_t)s3 * D + d);
        if (AFFINE) {
            h0.x = fmaf(h0.x, sc.x, sh.x); h0.y = fmaf(h0.y, sc.y, sh.y);
            h0.z = fmaf(h0.z, sc.z, sh.z); h0.w = fmaf(h0.w, sc.w, sh.w);
            h1.x = fmaf(h1.x, sc.x, sh.x); h1.y = fmaf(h1.y, sc.y, sh.y);
            h1.z = fmaf(h1.z, sc.z, sh.z); h1.w = fmaf(h1.w, sc.w, sh.w);
            h2.x = fmaf(h2.x, sc.x, sh.x); h2.y = fmaf(h2.y, sc.y, sh.y);
            h2.z = fmaf(h2.z, sc.z, sh.z); h2.w = fmaf(h2.w, sc.w, sh.w);
            h3.x = fmaf(h3.x, sc.x, sh.x); h3.y = fmaf(h3.y, sc.y, sh.y);
            h3.z = fmaf(h3.z, sc.z, sh.z); h3.w = fmaf(h3.w, sc.w, sh.w);
            h0.x = h0.x > 0.f ? h0.x : 0.f; h0.y = h0.y > 0.f ? h0.y : 0.f;
            h0.z = h0.z > 0.f ? h0.z : 0.f; h0.w = h0.w > 0.f ? h0.w : 0.f;
            h1.x = h1.x > 0.f ? h1.x : 0.f; h1.y = h1.y > 0.f ? h1.y : 0.f;
            h1.z = h1.z > 0.f ? h1.z : 0.f; h1.w = h1.w > 0.f ? h1.w : 0.f;
            h2.x = h2.x > 0.f ? h2.x : 0.f; h2.y = h2.y > 0.f ? h2.y : 0.f;
            h2.z = h2.z > 0.f ? h2.z : 0.f; h2.w = h2.w > 0.f ? h2.w : 0.f;
            h3.x = h3.x > 0.f ? h3.x : 0.f; h3.y = h3.y > 0.f ? h3.y : 0.f;
            h3.z = h3.z > 0.f ? h3.z : 0.f; h3.w = h3.w > 0.f ? h3.w : 0.f;
        }
        acc.x += (h0.x + h1.x) + (h2.x + h3.x);
        acc.y += (h0.y + h1.y) + (h2.y + h3.y);
        acc.z += (h0.z + h1.z) + (h2.z + h3.z);
        acc.w += (h0.w + h1.w) + (h2.w + h3.w);
    }
    for (; e < end; ++e) {
        float4 h0 = ldg4(hsrc + (size_t)esrc[e] * D + d);
        if (AFFINE) {
            h0.x = fmaf(h0.x, sc.x, sh.x); h0.y = fmaf(h0.y, sc.y, sh.y);
            h0.z = fmaf(h0.z, sc.z, sh.z); h0.w = fmaf(h0.w, sc.w, sh.w);
            h0.x = h0.x > 0.f ? h0.x : 0.f; h0.y = h0.y > 0.f ? h0.y : 0.f;
            h0.z = h0.z > 0.f ? h0.z : 0.f; h0.w = h0.w > 0.f ? h0.w : 0.f;
        }
        acc.x += h0.x; acc.y += h0.y; acc.z += h0.z; acc.w += h0.w;
    }

    // split fp32 -> bf16 hi + lo
    unsigned short h0 = f2bf(acc.x), h1 = f2bf(acc.y),
                   h2b = f2bf(acc.z), h3 = f2bf(acc.w);
    ushort4 hv = {h0, h1, h2b, h3};
    ushort4 lv = {f2bf(acc.x - bf2f(h0)), f2bf(acc.y - bf2f(h1)),
                  f2bf(acc.z - bf2f(h2b)), f2bf(acc.w - bf2f(h3))};
    unsigned short* op = aggp + (size_t)node * 256;
    *reinterpret_cast<ushort4*>(op + d) = hv;
    *reinterpret_cast<ushort4*>(op + D + d) = lv;
}

// ---------------------------------------------------------------------------
// Fused MLP on matrix cores, split-bf16 (3-term) for ~fp32 precision.
// Two 128-wide hidden phases reuse ONE 64x132 u32 LDS tile (34 KB) so 4
// blocks/CU fit (vs 2 at 69 KB). Tile stays wave-private (each wave touches
// only its 16 rows) -> no barriers in the GEMM path. Row stride 132 u32 =
// 33*16B (odd) -> ds_read_b128 16-lane pattern is bank-conflict-free.
// __launch_bounds__(256,4) caps VGPR at 128 (A-frags reloaded per phase).
// ---------------------------------------------------------------------------
__global__ __launch_bounds__(256, 4) void k_mlp(
    const unsigned short* __restrict__ aggp,   // [N][256] hi|lo
    float* __restrict__ h2,                    // [N][128] (= d_out)
    const unsigned short* __restrict__ W1p,    // this layer, packed frags
    const unsigned short* __restrict__ W2p,
    const float* __restrict__ b1, const float* __restrict__ b2,
    float* __restrict__ stats, int N)
{
    __shared__ unsigned int hid[64][132];      // 33792 B, row stride 528 B
    __shared__ float s_sum[D], s_sq[D];

    int t = threadIdx.x;
    if (t < D) { s_sum[t] = 0.f; s_sq[t] = 0.f; }
    __syncthreads();

    const int w = t >> 6, lane = t & 63;
    const int l15 = lane & 15, l4 = lane >> 4;
    const int row0 = blockIdx.x * 64;
    const int arow = row0 + (w << 4) + l15;    // A-operand row of this lane
    const int hrow = (w << 4) + l15;           // GEMM2 A row (block-local)
    const int drow_l = (w << 4) + (l4 << 2);   // epilogue row base (local)

    f32x4 acc2[8];
#pragma unroll
    for (int nt = 0; nt < 8; ++nt) acc2[nt] = f32x4{0.f, 0.f, 0.f, 0.f};

#pragma unroll
    for (int ph = 0; ph < 2; ++ph) {
        // ---- A fragments (reload per phase; L1-hot in phase 2) ----
        bh8 aHi[4], aLo[4];
        if (arow < N) {
            const unsigned short* ap = aggp + (size_t)arow * 256 + l4 * 8;
#pragma unroll
            for (int kk = 0; kk < 4; ++kk) {
                aHi[kk] = *reinterpret_cast<const bh8*>(ap + kk * 32);
                aLo[kk] = *reinterpret_cast<const bh8*>(ap + D + kk * 32);
            }
        } else {
#pragma unroll
            for (int kk = 0; kk < 4; ++kk) {
                aHi[kk] = bh8{0,0,0,0,0,0,0,0};
                aLo[kk] = bh8{0,0,0,0,0,0,0,0};
            }
        }

        // ---- GEMM1 half: [64x128] x [128x128] -> hidden cols ph*128.. ----
        f32x4 acc[8];
#pragma unroll
        for (int nt = 0; nt < 8; ++nt) acc[nt] = f32x4{0.f, 0.f, 0.f, 0.f};
#pragma unroll
        for (int nt = 0; nt < 8; ++nt) {
#pragma unroll
            for (int kk = 0; kk < 4; ++kk) {
                const unsigned short* bp =
                    W1p + (((ph * 8 + nt) * 4 + kk) * 64 + lane) * 16;
                bh8 bHi = *reinterpret_cast<const bh8*>(bp);
                bh8 bLo = *reinterpret_cast<const bh8*>(bp + 8);
                acc[nt] = __builtin_amdgcn_mfma_f32_16x16x32_bf16(aHi[kk], bHi, acc[nt], 0, 0, 0);
                acc[nt] = __builtin_amdgcn_mfma_f32_16x16x32_bf16(aHi[kk], bLo, acc[nt], 0, 0, 0);
                acc[nt] = __builtin_amdgcn_mfma_f32_16x16x32_bf16(aLo[kk], bHi, acc[nt], 0, 0, 0);
            }
        }

        // ---- epilogue: bias + relu + split -> hid (wave-private rows) ----
#pragma unroll
        for (int nt = 0; nt < 8; ++nt) {
            int lcol = nt * 16 + l15;
            float bias = b1[ph * 128 + lcol];
#pragma unroll
            for (int r = 0; r < 4; ++r) {
                float v = acc[nt][r] + bias;
                v = v > 0.f ? v : 0.f;
                unsigned short hi = f2bf(v);
                unsigned short lo = f2bf(v - bf2f(hi));
                hid[drow_l + r][lcol] = (unsigned int)hi | ((unsigned int)lo << 16);
            }
        }
        // same-wave write->read ordering via compiler lgkmcnt; no barrier

        // ---- GEMM2 partial: [64x128] x [128x128] accumulate into acc2 ----
#pragma unroll
        for (int kk = 0; kk < 4; ++kk) {
            uint4 w0 = *reinterpret_cast<const uint4*>(&hid[hrow][kk * 32 + l4 * 8]);
            uint4 w1 = *reinterpret_cast<const uint4*>(&hid[hrow][kk * 32 + l4 * 8 + 4]);
            bh8 hA, lA;
            hA[0] = (short)(w0.x & 0xffffu); lA[0] = (short)(w0.x >> 16);
            hA[1] = (short)(w0.y & 0xffffu); lA[1] = (short)(w0.y >> 16);
            hA[2] = (short)(w0.z & 0xffffu); lA[2] = (short)(w0.z >> 16);
            hA[3] = (short)(w0.w & 0xffffu); lA[3] = (short)(w0.w >> 16);
            hA[4] = (short)(w1.x & 0xffffu); lA[4] = (short)(w1.x >> 16);
            hA[5] = (short)(w1.y & 0xffffu); lA[5] = (short)(w1.y >> 16);
            hA[6] = (short)(w1.z & 0xffffu); lA[6] = (short)(w1.z >> 16);
            hA[7] = (short)(w1.w & 0xffffu); lA[7] = (short)(w1.w >> 16);
#pragma unroll
            for (int nt = 0; nt < 8; ++nt) {
                const unsigned short* bp =
                    W2p + ((nt * 8 + ph * 4 + kk) * 64 + lane) * 16;
                bh8 bHi = *reinterpret_cast<const bh8*>(bp);
                bh8 bLo = *reinterpret_cast<const bh8*>(bp + 8);
                acc2[nt] = __builtin_amdgcn_mfma_f32_16x16x32_bf16(hA, bHi, acc2[nt], 0, 0, 0);
                acc2[nt] = __builtin_amdgcn_mfma_f32_16x16x32_bf16(hA, bLo, acc2[nt], 0, 0, 0);
                acc2[nt] = __builtin_amdgcn_mfma_f32_16x16x32_bf16(lA, bHi, acc2[nt], 0, 0, 0);
            }
        }
    }

    // ---- epilogue2: bias + store h2 + BN partial sums ----
#pragma unroll
    for (int nt = 0; nt < 8; ++nt) {
        int col = nt * 16 + l15;
        float bias = b2[col];
        float cs = 0.f, cq = 0.f;
#pragma unroll
        for (int r = 0; r < 4; ++r) {
            int drow = row0 + drow_l + r;
            if (drow < N) {
                float v = acc2[nt][r] + bias;
                h2[(size_t)drow * D + col] = v;
                cs += v; cq += v * v;
            }
        }
        atomicAdd(&s_sum[col], cs);
        atomicAdd(&s_sq[col],  cq);
    }
    __syncthreads();
    if (t < D) {
        atomicAdd(stats + t,     s_sum[t]);
        atomicAdd(stats + D + t, s_sq[t]);
    }
}

// ---------------------------------------------------------------------------
// BN prep: scale/shift from sums
// ---------------------------------------------------------------------------
__global__ __launch_bounds__(128) void k_bnprep(
    const float* __restrict__ stats,
    const float* __restrict__ gamma, const float* __restrict__ beta,
    float* __restrict__ ss, float inv_n)
{
    int d = threadIdx.x;
    float mu  = stats[d] * inv_n;
    float var = stats[D + d] * inv_n - mu * mu;
    float sc  = rsqrtf(var + BN_EPS) * gamma[d];
    ss[d]     = sc;
    ss[D + d] = beta[d] - mu * sc;
}

// ---------------------------------------------------------------------------
// Final BN (no relu), in-place on d_out
// ---------------------------------------------------------------------------
__global__ __launch_bounds__(256) void k_bnfinal(
    float* __restrict__ h, const float* __restrict__ ss, int N)
{
    int idx = blockIdx.x * 256 + threadIdx.x;
    int row = idx >> 5;
    int d   = (idx & 31) * 4;
    if (row >= N) return;
    float4 v  = ldg4(h + (size_t)row * D + d);
    float4 sc = ldg4(ss + d);
    float4 sh = ldg4(ss + D + d);
    float4 o;
    o.x = fmaf(v.x, sc.x, sh.x);
    o.y = fmaf(v.y, sc.y, sh.y);
    o.z = fmaf(v.z, sc.z, sh.z);
    o.w = fmaf(v.w, sc.w, sh.w);
    *reinterpret_cast<float4*>(h + (size_t)row * D + d) = o;
}

// ---------------------------------------------------------------------------
static inline size_t align16(size_t x) { return (x + 15) & ~(size_t)15; }

extern "C" void kernel_launch(void* const* d_in, const int* in_sizes, int n_in,
                              void* d_out, int out_size, void* d_ws, size_t ws_size,
                              hipStream_t stream)
{
    const int*   x     = (const int*)  d_in[0];
    const int*   ei    = (const int*)  d_in[1];
    const int*   ea    = (const int*)  d_in[2];
    const float* ae1   = (const float*)d_in[3];
    const float* ae2   = (const float*)d_in[4];
    const float* be1   = (const float*)d_in[5];   // [5,7,128]
    const float* be2   = (const float*)d_in[6];   // [5,4,128]
    const float* W1    = (const float*)d_in[7];   // [5,128,256]
    const float* b1    = (const float*)d_in[8];   // [5,256]
    const float* W2    = (const float*)d_in[9];   // [5,256,128]
    const float* b2    = (const float*)d_in[10];  // [5,128]
    const float* gamma = (const float*)d_in[11];  // [5,128]
    const float* beta  = (const float*)d_in[12];  // [5,128]

    const int N = in_sizes[0] / 2;
    const int E = in_sizes[1] / 2;

    float* hbuf = (float*)d_out;   // h (layer 0) then h2 of each layer; final BN in place

    // ---- workspace layout (bytes) ----
    char* wsb = (char*)d_ws;
    size_t o = 0;
    int* rowptr = (int*)(wsb + o);          o += align16((size_t)(N + 1) * 4);
    int* counts = (int*)(wsb + o);          o += align16((size_t)N * 9 * 4);
    float* stats = (float*)(wsb + o);       o += align16((size_t)5 * 2 * D * 4);
    const size_t zero_bytes = o;            // rowptr+counts+stats zeroed together
    int* cursor = (int*)(wsb + o);          o += align16((size_t)N * 4);
    int* esrc = (int*)(wsb + o);            o += align16((size_t)E * 4);
    int* bsum = (int*)(wsb + o);            o += align16(1024 * 4);
    int* boff = (int*)(wsb + o);            o += align16(1024 * 4);
    float* ss = (float*)(wsb + o);          o += align16((size_t)5 * 2 * D * 4);
    float* bec = (float*)(wsb + o);         o += align16((size_t)5 * 10 * D * 4);
    unsigned short* W1p = (unsigned short*)(wsb + o); o += align16((size_t)5 * 65536 * 2);
    unsigned short* W2p = (unsigned short*)(wsb + o); o += align16((size_t)5 * 65536 * 2);
    unsigned short* aggp = (unsigned short*)(wsb + o); o += align16((size_t)N * 256 * 2);

    hipMemsetAsync(wsb, 0, zero_bytes, stream);

    const dim3 blk(256);
    const int nb_nodes  = (N * 32 + 255) / 256;
    const int nb_edges  = (E + 255) / 256;
    const int nchunks   = (N + 1023) / 1024;
    const int nb_gather = (N + 7) / 8;
    const int nb_mlp    = (N + 63) / 64;
    const float inv_n   = 1.0f / (float)N;

    k_atom<<<nb_nodes, blk, 0, stream>>>(x, ae1, ae2, hbuf, N);
    k_hist<<<nb_edges, blk, 0, stream>>>(ei, ea, rowptr, counts, E);
    k_scan1<<<nchunks, 1024, 0, stream>>>(rowptr, cursor, bsum, N);
    k_scan2<<<1, 64, 0, stream>>>(bsum, boff, nchunks);
    k_scan3<<<nchunks, 1024, 0, stream>>>(rowptr, cursor, boff, N);
    k_fill<<<nb_edges, blk, 0, stream>>>(ei, cursor, esrc, E);
    k_bec<<<(5 * 10 * D + 255) / 256, blk, 0, stream>>>(be1, be2, bec);
    k_wconv<<<(2 * 5 * 4096 + 255) / 256, blk, 0, stream>>>(W1, W2, W1p, W2p);

    for (int l = 0; l < 5; ++l) {
        float* st = stats + (size_t)l * 2 * D;
        const float* becl = bec + (size_t)l * 10 * D;
        if (l == 0) {
            k_gather<0><<<nb_gather, blk, 0, stream>>>(
                hbuf, rowptr, esrc, counts, becl, nullptr, aggp, N);
        } else {
            k_gather<1><<<nb_gather, blk, 0, stream>>>(
                hbuf, rowptr, esrc, counts, becl, ss + (size_t)(l - 1) * 2 * D, aggp, N);
        }
        k_mlp<<<nb_mlp, blk, 0, stream>>>(
            aggp, hbuf,
            W1p + (size_t)l * 65536, W2p + (size_t)l * 65536,
            b1 + (size_t)l * HD, b2 + (size_t)l * D, st, N);
        k_bnprep<<<1, 128, 0, stream>>>(st, gamma + (size_t)l * D,
                                        beta + (size_t)l * D,
                                        ss + (size_t)l * 2 * D, inv_n);
    }
    k_bnfinal<<<nb_nodes, blk, 0, stream>>>(hbuf, ss + (size_t)4 * 2 * D, N);
}

// Round 8
// 765.862 us; speedup vs baseline: 1.1414x; 1.1414x over previous
//
#include <hip/hip_runtime.h>

#define D 128
#define HD 256
#define BN_EPS 1e-5f

typedef __attribute__((ext_vector_type(8))) short bh8;
typedef __attribute__((ext_vector_type(4))) float f32x4;

__device__ __forceinline__ float4 ldg4(const float* p) {
    return *reinterpret_cast<const float4*>(p);
}
// bf16 RNE via bit ops
__device__ __forceinline__ unsigned short f2bf(float f) {
    union { float f; unsigned int u; } v; v.f = f;
    unsigned int u = v.u;
    return (unsigned short)((u + 0x7fffu + ((u >> 16) & 1u)) >> 16);
}
__device__ __forceinline__ float bf2f(unsigned short h) {
    union { unsigned int u; float f; } v; v.u = ((unsigned int)h) << 16; return v.f;
}

// ---------------------------------------------------------------------------
// K0: AtomEncoder  h[i] = atom_emb1[x[i,0]] + atom_emb2[x[i,1]]  -> d_out
// ---------------------------------------------------------------------------
__global__ __launch_bounds__(256) void k_atom(
    const int* __restrict__ x,
    const float* __restrict__ ae1, const float* __restrict__ ae2,
    float* __restrict__ h, int N)
{
    int idx = blockIdx.x * 256 + threadIdx.x;
    int row = idx >> 5;
    int d   = (idx & 31) * 4;
    if (row >= N) return;
    int i0 = x[row * 2 + 0];
    int i1 = x[row * 2 + 1];
    float4 a = ldg4(ae1 + (size_t)i0 * D + d);
    float4 b = ldg4(ae2 + (size_t)i1 * D + d);
    float4 o = {a.x + b.x, a.y + b.y, a.z + b.z, a.w + b.w};
    *reinterpret_cast<float4*>(h + (size_t)row * D + d) = o;
}

// ---------------------------------------------------------------------------
// CSR build 1: histogram degrees + per-(dst,combo) counts
// ---------------------------------------------------------------------------
__global__ __launch_bounds__(256) void k_hist(
    const int* __restrict__ ei, const int* __restrict__ ea,
    int* __restrict__ rowptr, int* __restrict__ counts, int E)
{
    int e = blockIdx.x * 256 + threadIdx.x;
    if (e >= E) return;
    int dst = ei[E + e];
    atomicAdd(&rowptr[dst + 1], 1);
    int c = ea[2 * e] * 3 + ea[2 * e + 1];
    atomicAdd(&counts[dst * 9 + c], 1);
}

// ---------------------------------------------------------------------------
// CSR build 2a/2b/2c: multi-block prefix sum
// ---------------------------------------------------------------------------
__global__ __launch_bounds__(1024) void k_scan1(
    int* __restrict__ rowptr, int* __restrict__ cursor,
    int* __restrict__ bsum, int N)
{
    __shared__ int wsum[16];
    int t = threadIdx.x, lane = t & 63, w = t >> 6;
    int i = blockIdx.x * 1024 + t;
    int v = (i < N) ? rowptr[i + 1] : 0;
    int incl = v;
#pragma unroll
    for (int off = 1; off < 64; off <<= 1) {
        int y = __shfl_up(incl, off);
        if (lane >= off) incl += y;
    }
    if (lane == 63) wsum[w] = incl;
    __syncthreads();
    if (t < 16) {
        int xv = wsum[t];
#pragma unroll
        for (int off = 1; off < 16; off <<= 1) {
            int y = __shfl_up(xv, off);
            if (t >= off) xv += y;
        }
        wsum[t] = xv;
    }
    __syncthreads();
    int woff = w ? wsum[w - 1] : 0;
    int full = woff + incl;
    if (i < N) { rowptr[i + 1] = full; cursor[i] = full - v; }
    if (t == 1023) bsum[blockIdx.x] = full;
}

__global__ __launch_bounds__(64) void k_scan2(
    const int* __restrict__ bsum, int* __restrict__ boff, int nchunks)
{
    int t = threadIdx.x;
    int carry = 0;
    for (int base = 0; base < nchunks; base += 64) {
        int idx = base + t;
        int v = (idx < nchunks) ? bsum[idx] : 0;
        int incl = v;
#pragma unroll
        for (int off = 1; off < 64; off <<= 1) {
            int y = __shfl_up(incl, off);
            if (t >= off) incl += y;
        }
        if (idx < nchunks) boff[idx] = carry + incl - v;
        carry += __shfl(incl, 63);
    }
}

__global__ __launch_bounds__(1024) void k_scan3(
    int* __restrict__ rowptr, int* __restrict__ cursor,
    const int* __restrict__ boff, int N)
{
    int t = threadIdx.x;
    int i = blockIdx.x * 1024 + t;
    int off = boff[blockIdx.x];
    if (i < N) { rowptr[i + 1] += off; cursor[i] += off; }
    if (blockIdx.x == 0 && t == 0) rowptr[0] = 0;
}

// ---------------------------------------------------------------------------
// CSR build 3: fill edge sources in CSR order
// ---------------------------------------------------------------------------
__global__ __launch_bounds__(256) void k_fill(
    const int* __restrict__ ei, int* __restrict__ cursor,
    int* __restrict__ esrc, int E)
{
    int e = blockIdx.x * 256 + threadIdx.x;
    if (e >= E) return;
    int dst = ei[E + e];
    int pos = atomicAdd(&cursor[dst], 1);
    esrc[pos] = ei[e];
}

// ---------------------------------------------------------------------------
// bec precompute
// ---------------------------------------------------------------------------
__global__ __launch_bounds__(256) void k_bec(
    const float* __restrict__ be1, const float* __restrict__ be2,
    float* __restrict__ bec)
{
    int idx = blockIdx.x * 256 + threadIdx.x;
    if (idx >= 5 * 10 * D) return;
    int d  = idx & (D - 1);
    int lc = idx >> 7;
    int l = lc / 10, c = lc % 10;
    int a0 = (c == 9) ? 6 : (c / 3);
    int a1 = (c == 9) ? 3 : (c % 3);
    bec[idx] = be1[((size_t)l * 7 + a0) * D + d] + be2[((size_t)l * 4 + a1) * D + d];
}

// ---------------------------------------------------------------------------
// Weight pack: split fp32 W into bf16 hi/lo, LDS-stage-friendly layout:
// per frag f (64 frags/layer): [64 lanes x 16B hi][64 lanes x 16B lo]
// = 2048 B/frag, 128 KB/layer. Element j of lane:
//   W1: f = nt*4+kk -> k = kk*32+(lane>>4)*8+j, n = nt*16+(lane&15)
//   W2: f = nt*8+kk -> k = kk*32+(lane>>4)*8+j, n = nt*16+(lane&15)
// ---------------------------------------------------------------------------
__global__ __launch_bounds__(256) void k_wconv(
    const float* __restrict__ W1, const float* __restrict__ W2,
    unsigned short* __restrict__ W1p, unsigned short* __restrict__ W2p)
{
    int tid = blockIdx.x * 256 + threadIdx.x;
    if (tid >= 2 * 5 * 4096) return;
    bool isW2 = tid >= 5 * 4096;
    int r  = tid & 4095;
    int l  = (tid % (5 * 4096)) >> 12;
    int f  = r >> 6;
    int lane = r & 63;
    int l15 = lane & 15, l4 = lane >> 4;
    const float* src;
    unsigned short* out;
    if (!isW2) {
        int nt = f >> 2, kk = f & 3;
        int n = nt * 16 + l15;
        int kbase = kk * 32 + l4 * 8;
        src = W1 + ((size_t)l * D + kbase) * HD + n;
        out = W1p + (size_t)l * 65536 + (size_t)f * 1024 + lane * 8;
#pragma unroll
        for (int j = 0; j < 8; ++j) {
            float wv = src[(size_t)j * HD];
            unsigned short hi = f2bf(wv);
            out[j] = hi; out[512 + j] = f2bf(wv - bf2f(hi));
        }
    } else {
        int nt = f >> 3, kk = f & 7;
        int n = nt * 16 + l15;
        int kbase = kk * 32 + l4 * 8;
        src = W2 + ((size_t)l * HD + kbase) * D + n;
        out = W2p + (size_t)l * 65536 + (size_t)f * 1024 + lane * 8;
#pragma unroll
        for (int j = 0; j < 8; ++j) {
            float wv = src[(size_t)j * D];
            unsigned short hi = f2bf(wv);
            out[j] = hi; out[512 + j] = f2bf(wv - bf2f(hi));
        }
    }
}

// ---------------------------------------------------------------------------
// Gather (+ fused BN affine + relu of previous layer), emits bf16 hi/lo agg.
// aggp row layout: 256 ushorts = [128 hi][128 lo].
// ---------------------------------------------------------------------------
template <int AFFINE>
__global__ __launch_bounds__(256) void k_gather(
    const float* __restrict__ hsrc, const int* __restrict__ rowptr,
    const int* __restrict__ esrc, const int* __restrict__ counts,
    const float* __restrict__ bec,
    const float* __restrict__ ss,
    unsigned short* __restrict__ aggp, int N)
{
    int g = threadIdx.x >> 5;
    int lane = threadIdx.x & 31;
    int d = lane * 4;
    int node = blockIdx.x * 8 + g;
    if (node >= N) return;

    float4 sc, sh;
    if (AFFINE) { sc = ldg4(ss + d); sh = ldg4(ss + D + d); }

    float4 acc = ldg4(hsrc + (size_t)node * D + d);
    if (AFFINE) {
        acc.x = fmaf(acc.x, sc.x, sh.x); acc.y = fmaf(acc.y, sc.y, sh.y);
        acc.z = fmaf(acc.z, sc.z, sh.z); acc.w = fmaf(acc.w, sc.w, sh.w);
        acc.x = acc.x > 0.f ? acc.x : 0.f; acc.y = acc.y > 0.f ? acc.y : 0.f;
        acc.z = acc.z > 0.f ? acc.z : 0.f; acc.w = acc.w > 0.f ? acc.w : 0.f;
    }
    float4 sl = ldg4(bec + 9 * D + d);
    acc.x += sl.x; acc.y += sl.y; acc.z += sl.z; acc.w += sl.w;

#pragma unroll
    for (int c = 0; c < 9; ++c) {
        float fc = (float)counts[node * 9 + c];
        float4 b = ldg4(bec + c * D + d);
        acc.x = fmaf(fc, b.x, acc.x);
        acc.y = fmaf(fc, b.y, acc.y);
        acc.z = fmaf(fc, b.z, acc.z);
        acc.w = fmaf(fc, b.w, acc.w);
    }

    int beg = rowptr[node], end = rowptr[node + 1];
    int e = beg;
    for (; e + 3 < end; e += 4) {
        int s0 = esrc[e], s1 = esrc[e + 1], s2 = esrc[e + 2], s3 = esrc[e + 3];
        float4 h0 = ldg4(hsrc + (size_t)s0 * D + d);
        float4 h1 = ldg4(hsrc + (size_t)s1 * D + d);
        float4 h2 = ldg4(hsrc + (size_t)s2 * D + d);
        float4 h3 = ldg4(hsrc + (size_t)s3 * D + d);
        if (AFFINE) {
            h0.x = fmaf(h0.x, sc.x, sh.x); h0.y = fmaf(h0.y, sc.y, sh.y);
            h0.z = fmaf(h0.z, sc.z, sh.z); h0.w = fmaf(h0.w, sc.w, sh.w);
            h1.x = fmaf(h1.x, sc.x, sh.x); h1.y = fmaf(h1.y, sc.y, sh.y);
            h1.z = fmaf(h1.z, sc.z, sh.z); h1.w = fmaf(h1.w, sc.w, sh.w);
            h2.x = fmaf(h2.x, sc.x, sh.x); h2.y = fmaf(h2.y, sc.y, sh.y);
            h2.z = fmaf(h2.z, sc.z, sh.z); h2.w = fmaf(h2.w, sc.w, sh.w);
            h3.x = fmaf(h3.x, sc.x, sh.x); h3.y = fmaf(h3.y, sc.y, sh.y);
            h3.z = fmaf(h3.z, sc.z, sh.z); h3.w = fmaf(h3.w, sc.w, sh.w);
            h0.x = h0.x > 0.f ? h0.x : 0.f; h0.y = h0.y > 0.f ? h0.y : 0.f;
            h0.z = h0.z > 0.f ? h0.z : 0.f; h0.w = h0.w > 0.f ? h0.w : 0.f;
            h1.x = h1.x > 0.f ? h1.x : 0.f; h1.y = h1.y > 0.f ? h1.y : 0.f;
            h1.z = h1.z > 0.f ? h1.z : 0.f; h1.w = h1.w > 0.f ? h1.w : 0.f;
            h2.x = h2.x > 0.f ? h2.x : 0.f; h2.y = h2.y > 0.f ? h2.y : 0.f;
            h2.z = h2.z > 0.f ? h2.z : 0.f; h2.w = h2.w > 0.f ? h2.w : 0.f;
            h3.x = h3.x > 0.f ? h3.x : 0.f; h3.y = h3.y > 0.f ? h3.y : 0.f;
            h3.z = h3.z > 0.f ? h3.z : 0.f; h3.w = h3.w > 0.f ? h3.w : 0.f;
        }
        acc.x += (h0.x + h1.x) + (h2.x + h3.x);
        acc.y += (h0.y + h1.y) + (h2.y + h3.y);
        acc.z += (h0.z + h1.z) + (h2.z + h3.z);
        acc.w += (h0.w + h1.w) + (h2.w + h3.w);
    }
    for (; e < end; ++e) {
        float4 h0 = ldg4(hsrc + (size_t)esrc[e] * D + d);
        if (AFFINE) {
            h0.x = fmaf(h0.x, sc.x, sh.x); h0.y = fmaf(h0.y, sc.y, sh.y);
            h0.z = fmaf(h0.z, sc.z, sh.z); h0.w = fmaf(h0.w, sc.w, sh.w);
            h0.x = h0.x > 0.f ? h0.x : 0.f; h0.y = h0.y > 0.f ? h0.y : 0.f;
            h0.z = h0.z > 0.f ? h0.z : 0.f; h0.w = h0.w > 0.f ? h0.w : 0.f;
        }
        acc.x += h0.x; acc.y += h0.y; acc.z += h0.z; acc.w += h0.w;
    }

    unsigned short h0 = f2bf(acc.x), h1 = f2bf(acc.y),
                   h2b = f2bf(acc.z), h3 = f2bf(acc.w);
    ushort4 hv = {h0, h1, h2b, h3};
    ushort4 lv = {f2bf(acc.x - bf2f(h0)), f2bf(acc.y - bf2f(h1)),
                  f2bf(acc.z - bf2f(h2b)), f2bf(acc.w - bf2f(h3))};
    unsigned short* op = aggp + (size_t)node * 256;
    *reinterpret_cast<ushort4*>(op + d) = hv;
    *reinterpret_cast<ushort4*>(op + D + d) = lv;
}

// ---------------------------------------------------------------------------
// M1: GEMM1 + bias + relu + bf16-split. W1 (128 KB) staged in LDS; B-frags
// are conflict-free ds_read_b128 (lane-contiguous 16 B). 1024 thr = 16 waves,
// 1 block/CU, wave tile = 16 rows. Hidden (packed u32 hi|lo) overwrites:
//   cols 0..127  -> hidA (= aggp reinterpreted)   [rows read first, WAR-safe]
//   cols 128..255-> hidB (= hbuf reinterpreted)   [h is dead here]
// ---------------------------------------------------------------------------
__global__ __launch_bounds__(1024) void k_m1(
    const unsigned short* __restrict__ aggp,   // [N][256] hi|lo (read)
    unsigned int* hidA,                        // aliases aggp (write)
    unsigned int* hidB,                        // aliases hbuf (write)
    const unsigned short* __restrict__ W1p,    // layer slice, 65536 ushorts
    const float* __restrict__ b1, int N)
{
    __shared__ uint4 wlds[8192];               // 128 KB
    int t = threadIdx.x;
    {
        const uint4* src = (const uint4*)W1p;
        for (int i = t; i < 8192; i += 1024) wlds[i] = src[i];
    }
    __syncthreads();                           // no barriers after this

    int w = t >> 6, lane = t & 63;
    int l15 = lane & 15, l4 = lane >> 4;
    int tile = blockIdx.x * 16 + w;
    int row0 = tile * 16;
    if (row0 >= N) return;

    int arow = row0 + l15;
    bh8 aHi[4], aLo[4];
    if (arow < N) {
        const unsigned short* ap = aggp + (size_t)arow * 256 + l4 * 8;
#pragma unroll
        for (int kk = 0; kk < 4; ++kk) {
            aHi[kk] = *reinterpret_cast<const bh8*>(ap + kk * 32);
            aLo[kk] = *reinterpret_cast<const bh8*>(ap + D + kk * 32);
        }
    } else {
#pragma unroll
        for (int kk = 0; kk < 4; ++kk) {
            aHi[kk] = bh8{0,0,0,0,0,0,0,0};
            aLo[kk] = bh8{0,0,0,0,0,0,0,0};
        }
    }

    const char* wl = (const char*)wlds;
    int drow_base = row0 + (l4 << 2);

#pragma unroll
    for (int nt = 0; nt < 16; ++nt) {
        f32x4 a = f32x4{0.f, 0.f, 0.f, 0.f};
#pragma unroll
        for (int kk = 0; kk < 4; ++kk) {
            int fb = ((nt << 2) | kk) << 11;   // frag * 2048 B
            bh8 bHi = *reinterpret_cast<const bh8*>(wl + fb + (lane << 4));
            bh8 bLo = *reinterpret_cast<const bh8*>(wl + fb + 1024 + (lane << 4));
            a = __builtin_amdgcn_mfma_f32_16x16x32_bf16(aHi[kk], bHi, a, 0, 0, 0);
            a = __builtin_amdgcn_mfma_f32_16x16x32_bf16(aHi[kk], bLo, a, 0, 0, 0);
            a = __builtin_amdgcn_mfma_f32_16x16x32_bf16(aLo[kk], bHi, a, 0, 0, 0);
        }
        int col = (nt << 4) + l15;
        float bias = b1[col];
#pragma unroll
        for (int r = 0; r < 4; ++r) {
            int drow = drow_base + r;
            if (drow < N) {
                float v = a[r] + bias;
                v = v > 0.f ? v : 0.f;
                unsigned short hi = f2bf(v);
                unsigned short lo = f2bf(v - bf2f(hi));
                unsigned int pv = (unsigned int)hi | ((unsigned int)lo << 16);
                if (col < 128) hidA[(size_t)drow * 128 + col] = pv;
                else           hidB[(size_t)drow * 128 + col - 128] = pv;
            }
        }
    }
}

// ---------------------------------------------------------------------------
// M2: GEMM2 + bias + BN stats. W2 (128 KB) in LDS. Reads hidden u32 from
// hidA/hidB; writes h2 fp32 into hbuf (same rows it read -> WAR-safe within
// wave via the MFMA data dependency).
// ---------------------------------------------------------------------------
__global__ __launch_bounds__(1024) void k_m2(
    const unsigned int* hidA,                  // aliases aggp
    const unsigned int* hidB,                  // aliases hbuf
    float* h2,                                 // = hbuf
    const unsigned short* __restrict__ W2p,    // layer slice
    const float* __restrict__ b2,
    float* __restrict__ stats, int N)
{
    __shared__ uint4 wlds[8192];               // 128 KB
    __shared__ float s_sum[D], s_sq[D];
    int t = threadIdx.x;
    {
        const uint4* src = (const uint4*)W2p;
        for (int i = t; i < 8192; i += 1024) wlds[i] = src[i];
    }
    if (t < D) { s_sum[t] = 0.f; s_sq[t] = 0.f; }
    __syncthreads();

    int w = t >> 6, lane = t & 63;
    int l15 = lane & 15, l4 = lane >> 4;
    int tile = blockIdx.x * 16 + w;
    int row0 = tile * 16;
    bool active = row0 < N;

    if (active) {
        int arow = row0 + l15;
        const char* wl = (const char*)wlds;
        f32x4 acc2[8];
#pragma unroll
        for (int nt = 0; nt < 8; ++nt) acc2[nt] = f32x4{0.f, 0.f, 0.f, 0.f};

#pragma unroll
        for (int kk = 0; kk < 8; ++kk) {
            uint4 w0, w1;
            if (arow < N) {
                const unsigned int* base = (kk < 4)
                    ? (hidA + (size_t)arow * 128 + kk * 32 + l4 * 8)
                    : (hidB + (size_t)arow * 128 + (kk - 4) * 32 + l4 * 8);
                w0 = *reinterpret_cast<const uint4*>(base);
                w1 = *reinterpret_cast<const uint4*>(base + 4);
            } else {
                w0 = uint4{0,0,0,0}; w1 = uint4{0,0,0,0};
            }
            bh8 hA, lA;
            hA[0] = (short)(w0.x & 0xffffu); lA[0] = (short)(w0.x >> 16);
            hA[1] = (short)(w0.y & 0xffffu); lA[1] = (short)(w0.y >> 16);
            hA[2] = (short)(w0.z & 0xffffu); lA[2] = (short)(w0.z >> 16);
            hA[3] = (short)(w0.w & 0xffffu); lA[3] = (short)(w0.w >> 16);
            hA[4] = (short)(w1.x & 0xffffu); lA[4] = (short)(w1.x >> 16);
            hA[5] = (short)(w1.y & 0xffffu); lA[5] = (short)(w1.y >> 16);
            hA[6] = (short)(w1.z & 0xffffu); lA[6] = (short)(w1.z >> 16);
            hA[7] = (short)(w1.w & 0xffffu); lA[7] = (short)(w1.w >> 16);
#pragma unroll
            for (int nt = 0; nt < 8; ++nt) {
                int fb = ((nt << 3) | kk) << 11;
                bh8 bHi = *reinterpret_cast<const bh8*>(wl + fb + (lane << 4));
                bh8 bLo = *reinterpret_cast<const bh8*>(wl + fb + 1024 + (lane << 4));
                acc2[nt] = __builtin_amdgcn_mfma_f32_16x16x32_bf16(hA, bHi, acc2[nt], 0, 0, 0);
                acc2[nt] = __builtin_amdgcn_mfma_f32_16x16x32_bf16(hA, bLo, acc2[nt], 0, 0, 0);
                acc2[nt] = __builtin_amdgcn_mfma_f32_16x16x32_bf16(lA, bHi, acc2[nt], 0, 0, 0);
            }
        }

        int drow_base = row0 + (l4 << 2);
#pragma unroll
        for (int nt = 0; nt < 8; ++nt) {
            int col = (nt << 4) + l15;
            float bias = b2[col];
            float cs = 0.f, cq = 0.f;
#pragma unroll
            for (int r = 0; r < 4; ++r) {
                int drow = drow_base + r;
                if (drow < N) {
                    float v = acc2[nt][r] + bias;
                    h2[(size_t)drow * 128 + col] = v;
                    cs += v; cq += v * v;
                }
            }
            atomicAdd(&s_sum[col], cs);
            atomicAdd(&s_sq[col],  cq);
        }
    }
    __syncthreads();
    if (t < D) {
        atomicAdd(stats + t,     s_sum[t]);
        atomicAdd(stats + D + t, s_sq[t]);
    }
}

// ---------------------------------------------------------------------------
// BN prep: scale/shift from sums
// ---------------------------------------------------------------------------
__global__ __launch_bounds__(128) void k_bnprep(
    const float* __restrict__ stats,
    const float* __restrict__ gamma, const float* __restrict__ beta,
    float* __restrict__ ss, float inv_n)
{
    int d = threadIdx.x;
    float mu  = stats[d] * inv_n;
    float var = stats[D + d] * inv_n - mu * mu;
    float sc  = rsqrtf(var + BN_EPS) * gamma[d];
    ss[d]     = sc;
    ss[D + d] = beta[d] - mu * sc;
}

// ---------------------------------------------------------------------------
// Final BN (no relu), in-place on d_out
// ---------------------------------------------------------------------------
__global__ __launch_bounds__(256) void k_bnfinal(
    float* __restrict__ h, const float* __restrict__ ss, int N)
{
    int idx = blockIdx.x * 256 + threadIdx.x;
    int row = idx >> 5;
    int d   = (idx & 31) * 4;
    if (row >= N) return;
    float4 v  = ldg4(h + (size_t)row * D + d);
    float4 sc = ldg4(ss + d);
    float4 sh = ldg4(ss + D + d);
    float4 o;
    o.x = fmaf(v.x, sc.x, sh.x);
    o.y = fmaf(v.y, sc.y, sh.y);
    o.z = fmaf(v.z, sc.z, sh.z);
    o.w = fmaf(v.w, sc.w, sh.w);
    *reinterpret_cast<float4*>(h + (size_t)row * D + d) = o;
}

// ---------------------------------------------------------------------------
static inline size_t align16(size_t x) { return (x + 15) & ~(size_t)15; }

extern "C" void kernel_launch(void* const* d_in, const int* in_sizes, int n_in,
                              void* d_out, int out_size, void* d_ws, size_t ws_size,
                              hipStream_t stream)
{
    const int*   x     = (const int*)  d_in[0];
    const int*   ei    = (const int*)  d_in[1];
    const int*   ea    = (const int*)  d_in[2];
    const float* ae1   = (const float*)d_in[3];
    const float* ae2   = (const float*)d_in[4];
    const float* be1   = (const float*)d_in[5];   // [5,7,128]
    const float* be2   = (const float*)d_in[6];   // [5,4,128]
    const float* W1    = (const float*)d_in[7];   // [5,128,256]
    const float* b1    = (const float*)d_in[8];   // [5,256]
    const float* W2    = (const float*)d_in[9];   // [5,256,128]
    const float* b2    = (const float*)d_in[10];  // [5,128]
    const float* gamma = (const float*)d_in[11];  // [5,128]
    const float* beta  = (const float*)d_in[12];  // [5,128]

    const int N = in_sizes[0] / 2;
    const int E = in_sizes[1] / 2;

    float* hbuf = (float*)d_out;

    // ---- workspace layout (bytes) ----
    char* wsb = (char*)d_ws;
    size_t o = 0;
    int* rowptr = (int*)(wsb + o);          o += align16((size_t)(N + 1) * 4);
    int* counts = (int*)(wsb + o);          o += align16((size_t)N * 9 * 4);
    float* stats = (float*)(wsb + o);       o += align16((size_t)5 * 2 * D * 4);
    const size_t zero_bytes = o;
    int* cursor = (int*)(wsb + o);          o += align16((size_t)N * 4);
    int* esrc = (int*)(wsb + o);            o += align16((size_t)E * 4);
    int* bsum = (int*)(wsb + o);            o += align16(1024 * 4);
    int* boff = (int*)(wsb + o);            o += align16(1024 * 4);
    float* ss = (float*)(wsb + o);          o += align16((size_t)5 * 2 * D * 4);
    float* bec = (float*)(wsb + o);         o += align16((size_t)5 * 10 * D * 4);
    unsigned short* W1p = (unsigned short*)(wsb + o); o += align16((size_t)5 * 65536 * 2);
    unsigned short* W2p = (unsigned short*)(wsb + o); o += align16((size_t)5 * 65536 * 2);
    unsigned short* aggp = (unsigned short*)(wsb + o); o += align16((size_t)N * 256 * 2);

    hipMemsetAsync(wsb, 0, zero_bytes, stream);

    const dim3 blk(256);
    const int nb_nodes  = (N * 32 + 255) / 256;
    const int nb_edges  = (E + 255) / 256;
    const int nchunks   = (N + 1023) / 1024;
    const int nb_gather = (N + 7) / 8;
    const int ntiles    = (N + 15) / 16;
    const int nb_m      = (ntiles + 15) / 16;   // 16 waves/block
    const float inv_n   = 1.0f / (float)N;

    unsigned int* hidA = (unsigned int*)aggp;
    unsigned int* hidB = (unsigned int*)hbuf;

    k_atom<<<nb_nodes, blk, 0, stream>>>(x, ae1, ae2, hbuf, N);
    k_hist<<<nb_edges, blk, 0, stream>>>(ei, ea, rowptr, counts, E);
    k_scan1<<<nchunks, 1024, 0, stream>>>(rowptr, cursor, bsum, N);
    k_scan2<<<1, 64, 0, stream>>>(bsum, boff, nchunks);
    k_scan3<<<nchunks, 1024, 0, stream>>>(rowptr, cursor, boff, N);
    k_fill<<<nb_edges, blk, 0, stream>>>(ei, cursor, esrc, E);
    k_bec<<<(5 * 10 * D + 255) / 256, blk, 0, stream>>>(be1, be2, bec);
    k_wconv<<<(2 * 5 * 4096 + 255) / 256, blk, 0, stream>>>(W1, W2, W1p, W2p);

    for (int l = 0; l < 5; ++l) {
        float* st = stats + (size_t)l * 2 * D;
        const float* becl = bec + (size_t)l * 10 * D;
        if (l == 0) {
            k_gather<0><<<nb_gather, blk, 0, stream>>>(
                hbuf, rowptr, esrc, counts, becl, nullptr, aggp, N);
        } else {
            k_gather<1><<<nb_gather, blk, 0, stream>>>(
                hbuf, rowptr, esrc, counts, becl, ss + (size_t)(l - 1) * 2 * D, aggp, N);
        }
        k_m1<<<nb_m, 1024, 0, stream>>>(
            aggp, hidA, hidB,
            W1p + (size_t)l * 65536, b1 + (size_t)l * HD, N);
        k_m2<<<nb_m, 1024, 0, stream>>>(
            hidA, hidB, hbuf,
            W2p + (size_t)l * 65536, b2 + (size_t)l * D, st, N);
        k_bnprep<<<1, 128, 0, stream>>>(st, gamma + (size_t)l * D,
                                        beta + (size_t)l * D,
                                        ss + (size_t)l * 2 * D, inv_n);
    }
    k_bnfinal<<<nb_nodes, blk, 0, stream>>>(hbuf, ss + (size_t)4 * 2 * D, N);
}

// Round 9
// 717.087 us; speedup vs baseline: 1.2191x; 1.0680x over previous
//
#include <hip/hip_runtime.h>

#define D 128
#define HD 256
#define BN_EPS 1e-5f

typedef __attribute__((ext_vector_type(8))) _Float16 h8;
typedef __attribute__((ext_vector_type(4))) float f32x4;

__device__ __forceinline__ float4 ldg4(const float* p) {
    return *reinterpret_cast<const float4*>(p);
}
// f32 <-> f16 bit helpers (RNE)
__device__ __forceinline__ unsigned short f2h_bits(float f) {
    union { _Float16 h; unsigned short u; } c; c.h = (_Float16)f; return c.u;
}
__device__ __forceinline__ float h2f(unsigned short b) {
    union { unsigned short u; _Float16 h; } c; c.u = b; return (float)c.h;
}

// ---------------------------------------------------------------------------
// K0: AtomEncoder  h[i] = atom_emb1[x[i,0]] + atom_emb2[x[i,1]]  -> d_out
// ---------------------------------------------------------------------------
__global__ __launch_bounds__(256) void k_atom(
    const int* __restrict__ x,
    const float* __restrict__ ae1, const float* __restrict__ ae2,
    float* __restrict__ h, int N)
{
    int idx = blockIdx.x * 256 + threadIdx.x;
    int row = idx >> 5;
    int d   = (idx & 31) * 4;
    if (row >= N) return;
    int i0 = x[row * 2 + 0];
    int i1 = x[row * 2 + 1];
    float4 a = ldg4(ae1 + (size_t)i0 * D + d);
    float4 b = ldg4(ae2 + (size_t)i1 * D + d);
    float4 o = {a.x + b.x, a.y + b.y, a.z + b.z, a.w + b.w};
    *reinterpret_cast<float4*>(h + (size_t)row * D + d) = o;
}

// ---------------------------------------------------------------------------
// CSR build 1: ONE atomic per edge (counts only; degree derived in scan1)
// ---------------------------------------------------------------------------
__global__ __launch_bounds__(256) void k_hist(
    const int* __restrict__ ei, const int* __restrict__ ea,
    int* __restrict__ counts, int E)
{
    int e = blockIdx.x * 256 + threadIdx.x;
    if (e >= E) return;
    int dst = ei[E + e];
    int c = ea[2 * e] * 3 + ea[2 * e + 1];
    atomicAdd(&counts[dst * 9 + c], 1);
}

// ---------------------------------------------------------------------------
// CSR build 2a/2b/2c: multi-block prefix sum; deg(i) = sum of counts[i][0..9)
// ---------------------------------------------------------------------------
__global__ __launch_bounds__(1024) void k_scan1(
    const int* __restrict__ counts,
    int* __restrict__ rowptr, int* __restrict__ cursor,
    int* __restrict__ bsum, int N)
{
    __shared__ int wsum[16];
    int t = threadIdx.x, lane = t & 63, w = t >> 6;
    int i = blockIdx.x * 1024 + t;
    int v = 0;
    if (i < N) {
        const int* cp = counts + (size_t)i * 9;
#pragma unroll
        for (int j = 0; j < 9; ++j) v += cp[j];
    }
    int incl = v;
#pragma unroll
    for (int off = 1; off < 64; off <<= 1) {
        int y = __shfl_up(incl, off);
        if (lane >= off) incl += y;
    }
    if (lane == 63) wsum[w] = incl;
    __syncthreads();
    if (t < 16) {
        int xv = wsum[t];
#pragma unroll
        for (int off = 1; off < 16; off <<= 1) {
            int y = __shfl_up(xv, off);
            if (t >= off) xv += y;
        }
        wsum[t] = xv;
    }
    __syncthreads();
    int woff = w ? wsum[w - 1] : 0;
    int full = woff + incl;
    if (i < N) { rowptr[i + 1] = full; cursor[i] = full - v; }
    if (t == 1023) bsum[blockIdx.x] = full;
}

__global__ __launch_bounds__(64) void k_scan2(
    const int* __restrict__ bsum, int* __restrict__ boff, int nchunks)
{
    int t = threadIdx.x;
    int carry = 0;
    for (int base = 0; base < nchunks; base += 64) {
        int idx = base + t;
        int v = (idx < nchunks) ? bsum[idx] : 0;
        int incl = v;
#pragma unroll
        for (int off = 1; off < 64; off <<= 1) {
            int y = __shfl_up(incl, off);
            if (t >= off) incl += y;
        }
        if (idx < nchunks) boff[idx] = carry + incl - v;
        carry += __shfl(incl, 63);
    }
}

__global__ __launch_bounds__(1024) void k_scan3(
    int* __restrict__ rowptr, int* __restrict__ cursor,
    const int* __restrict__ boff, int N)
{
    int t = threadIdx.x;
    int i = blockIdx.x * 1024 + t;
    int off = boff[blockIdx.x];
    if (i < N) { rowptr[i + 1] += off; cursor[i] += off; }
    if (blockIdx.x == 0 && t == 0) rowptr[0] = 0;
}

// ---------------------------------------------------------------------------
// CSR build 3: fill edge sources in CSR order
// ---------------------------------------------------------------------------
__global__ __launch_bounds__(256) void k_fill(
    const int* __restrict__ ei, int* __restrict__ cursor,
    int* __restrict__ esrc, int E)
{
    int e = blockIdx.x * 256 + threadIdx.x;
    if (e >= E) return;
    int dst = ei[E + e];
    int pos = atomicAdd(&cursor[dst], 1);
    esrc[pos] = ei[e];
}

// ---------------------------------------------------------------------------
// bec precompute
// ---------------------------------------------------------------------------
__global__ __launch_bounds__(256) void k_bec(
    const float* __restrict__ be1, const float* __restrict__ be2,
    float* __restrict__ bec)
{
    int idx = blockIdx.x * 256 + threadIdx.x;
    if (idx >= 5 * 10 * D) return;
    int d  = idx & (D - 1);
    int lc = idx >> 7;
    int l = lc / 10, c = lc % 10;
    int a0 = (c == 9) ? 6 : (c / 3);
    int a1 = (c == 9) ? 3 : (c % 3);
    bec[idx] = be1[((size_t)l * 7 + a0) * D + d] + be2[((size_t)l * 4 + a1) * D + d];
}

// ---------------------------------------------------------------------------
// Weight pack: single f16 per element, fragment-ordered for LDS staging.
// Per frag f: 64 lanes x 16B (h8) = 1024 B. 64 frags/layer = 64 KB.
//   W1: f = nt*4+kk -> k = kk*32+(lane>>4)*8+j, n = nt*16+(lane&15)
//   W2: f = nt*8+kk -> same element mapping
// ---------------------------------------------------------------------------
__global__ __launch_bounds__(256) void k_wconv(
    const float* __restrict__ W1, const float* __restrict__ W2,
    unsigned short* __restrict__ W1p, unsigned short* __restrict__ W2p)
{
    int tid = blockIdx.x * 256 + threadIdx.x;
    if (tid >= 2 * 5 * 4096) return;
    bool isW2 = tid >= 5 * 4096;
    int r  = tid & 4095;
    int l  = (tid % (5 * 4096)) >> 12;
    int f  = r >> 6;
    int lane = r & 63;
    int l15 = lane & 15, l4 = lane >> 4;
    if (!isW2) {
        int nt = f >> 2, kk = f & 3;
        int n = nt * 16 + l15;
        int kbase = kk * 32 + l4 * 8;
        const float* src = W1 + ((size_t)l * D + kbase) * HD + n;
        unsigned short* out = W1p + (size_t)l * 32768 + (size_t)f * 512 + lane * 8;
#pragma unroll
        for (int j = 0; j < 8; ++j) out[j] = f2h_bits(src[(size_t)j * HD]);
    } else {
        int nt = f >> 3, kk = f & 7;
        int n = nt * 16 + l15;
        int kbase = kk * 32 + l4 * 8;
        const float* src = W2 + ((size_t)l * HD + kbase) * D + n;
        unsigned short* out = W2p + (size_t)l * 32768 + (size_t)f * 512 + lane * 8;
#pragma unroll
        for (int j = 0; j < 8; ++j) out[j] = f2h_bits(src[(size_t)j * D]);
    }
}

// ---------------------------------------------------------------------------
// Gather (+ fused BN affine + relu of previous layer), emits f16 hi/lo agg.
// aggp row layout: 256 ushorts = [128 hi][128 lo] (f16 bits).
// ---------------------------------------------------------------------------
template <int AFFINE>
__global__ __launch_bounds__(256) void k_gather(
    const float* __restrict__ hsrc, const int* __restrict__ rowptr,
    const int* __restrict__ esrc, const int* __restrict__ counts,
    const float* __restrict__ bec,
    const float* __restrict__ ss,
    unsigned short* __restrict__ aggp, int N)
{
    int g = threadIdx.x >> 5;
    int lane = threadIdx.x & 31;
    int d = lane * 4;
    int node = blockIdx.x * 8 + g;
    if (node >= N) return;

    float4 sc, sh;
    if (AFFINE) { sc = ldg4(ss + d); sh = ldg4(ss + D + d); }

    float4 acc = ldg4(hsrc + (size_t)node * D + d);
    if (AFFINE) {
        acc.x = fmaf(acc.x, sc.x, sh.x); acc.y = fmaf(acc.y, sc.y, sh.y);
        acc.z = fmaf(acc.z, sc.z, sh.z); acc.w = fmaf(acc.w, sc.w, sh.w);
        acc.x = acc.x > 0.f ? acc.x : 0.f; acc.y = acc.y > 0.f ? acc.y : 0.f;
        acc.z = acc.z > 0.f ? acc.z : 0.f; acc.w = acc.w > 0.f ? acc.w : 0.f;
    }
    float4 sl = ldg4(bec + 9 * D + d);
    acc.x += sl.x; acc.y += sl.y; acc.z += sl.z; acc.w += sl.w;

#pragma unroll
    for (int c = 0; c < 9; ++c) {
        float fc = (float)counts[node * 9 + c];
        float4 b = ldg4(bec + c * D + d);
        acc.x = fmaf(fc, b.x, acc.x);
        acc.y = fmaf(fc, b.y, acc.y);
        acc.z = fmaf(fc, b.z, acc.z);
        acc.w = fmaf(fc, b.w, acc.w);
    }

    int beg = rowptr[node], end = rowptr[node + 1];
    int e = beg;
    for (; e + 3 < end; e += 4) {
        int s0 = esrc[e], s1 = esrc[e + 1], s2 = esrc[e + 2], s3 = esrc[e + 3];
        float4 h0 = ldg4(hsrc + (size_t)s0 * D + d);
        float4 h1 = ldg4(hsrc + (size_t)s1 * D + d);
        float4 h2 = ldg4(hsrc + (size_t)s2 * D + d);
        float4 h3 = ldg4(hsrc + (size_t)s3 * D + d);
        if (AFFINE) {
            h0.x = fmaf(h0.x, sc.x, sh.x); h0.y = fmaf(h0.y, sc.y, sh.y);
            h0.z = fmaf(h0.z, sc.z, sh.z); h0.w = fmaf(h0.w, sc.w, sh.w);
            h1.x = fmaf(h1.x, sc.x, sh.x); h1.y = fmaf(h1.y, sc.y, sh.y);
            h1.z = fmaf(h1.z, sc.z, sh.z); h1.w = fmaf(h1.w, sc.w, sh.w);
            h2.x = fmaf(h2.x, sc.x, sh.x); h2.y = fmaf(h2.y, sc.y, sh.y);
            h2.z = fmaf(h2.z, sc.z, sh.z); h2.w = fmaf(h2.w, sc.w, sh.w);
            h3.x = fmaf(h3.x, sc.x, sh.x); h3.y = fmaf(h3.y, sc.y, sh.y);
            h3.z = fmaf(h3.z, sc.z, sh.z); h3.w = fmaf(h3.w, sc.w, sh.w);
            h0.x = h0.x > 0.f ? h0.x : 0.f; h0.y = h0.y > 0.f ? h0.y : 0.f;
            h0.z = h0.z > 0.f ? h0.z : 0.f; h0.w = h0.w > 0.f ? h0.w : 0.f;
            h1.x = h1.x > 0.f ? h1.x : 0.f; h1.y = h1.y > 0.f ? h1.y : 0.f;
            h1.z = h1.z > 0.f ? h1.z : 0.f; h1.w = h1.w > 0.f ? h1.w : 0.f;
            h2.x = h2.x > 0.f ? h2.x : 0.f; h2.y = h2.y > 0.f ? h2.y : 0.f;
            h2.z = h2.z > 0.f ? h2.z : 0.f; h2.w = h2.w > 0.f ? h2.w : 0.f;
            h3.x = h3.x > 0.f ? h3.x : 0.f; h3.y = h3.y > 0.f ? h3.y : 0.f;
            h3.z = h3.z > 0.f ? h3.z : 0.f; h3.w = h3.w > 0.f ? h3.w : 0.f;
        }
        acc.x += (h0.x + h1.x) + (h2.x + h3.x);
        acc.y += (h0.y + h1.y) + (h2.y + h3.y);
        acc.z += (h0.z + h1.z) + (h2.z + h3.z);
        acc.w += (h0.w + h1.w) + (h2.w + h3.w);
    }
    for (; e < end; ++e) {
        float4 h0 = ldg4(hsrc + (size_t)esrc[e] * D + d);
        if (AFFINE) {
            h0.x = fmaf(h0.x, sc.x, sh.x); h0.y = fmaf(h0.y, sc.y, sh.y);
            h0.z = fmaf(h0.z, sc.z, sh.z); h0.w = fmaf(h0.w, sc.w, sh.w);
            h0.x = h0.x > 0.f ? h0.x : 0.f; h0.y = h0.y > 0.f ? h0.y : 0.f;
            h0.z = h0.z > 0.f ? h0.z : 0.f; h0.w = h0.w > 0.f ? h0.w : 0.f;
        }
        acc.x += h0.x; acc.y += h0.y; acc.z += h0.z; acc.w += h0.w;
    }

    unsigned short h0 = f2h_bits(acc.x), h1 = f2h_bits(acc.y),
                   h2b = f2h_bits(acc.z), h3 = f2h_bits(acc.w);
    ushort4 hv = {h0, h1, h2b, h3};
    ushort4 lv = {f2h_bits(acc.x - h2f(h0)), f2h_bits(acc.y - h2f(h1)),
                  f2h_bits(acc.z - h2f(h2b)), f2h_bits(acc.w - h2f(h3))};
    unsigned short* op = aggp + (size_t)node * 256;
    *reinterpret_cast<ushort4*>(op + d) = hv;
    *reinterpret_cast<ushort4*>(op + D + d) = lv;
}

// ---------------------------------------------------------------------------
// M1: GEMM1 + bias + relu + f16-split. W1 (64 KB f16) staged in LDS.
// 2-term MFMA: aHi*W + aLo*W (W f16-RNE; rel err ~2^-12).
// 1024 thr = 16 waves, wave tile = 16 rows. Hidden (u32 hi|lo) overwrites
// aggp (cols 0..127) and hbuf (cols 128..255) rows (WAR-safe per wave).
// ---------------------------------------------------------------------------
__global__ __launch_bounds__(1024) void k_m1(
    const unsigned short* __restrict__ aggp,   // [N][256] hi|lo (read)
    unsigned int* hidA,                        // aliases aggp (write)
    unsigned int* hidB,                        // aliases hbuf (write)
    const unsigned short* __restrict__ W1p,    // layer slice, 32768 ushorts
    const float* __restrict__ b1, int N)
{
    __shared__ uint4 wlds[4096];               // 64 KB
    int t = threadIdx.x;
    {
        const uint4* src = (const uint4*)W1p;
        for (int i = t; i < 4096; i += 1024) wlds[i] = src[i];
    }
    __syncthreads();                           // no barriers after this

    int w = t >> 6, lane = t & 63;
    int l15 = lane & 15, l4 = lane >> 4;
    int tile = blockIdx.x * 16 + w;
    int row0 = tile * 16;
    if (row0 >= N) return;

    int arow = row0 + l15;
    h8 aHi[4], aLo[4];
    if (arow < N) {
        const unsigned short* ap = aggp + (size_t)arow * 256 + l4 * 8;
#pragma unroll
        for (int kk = 0; kk < 4; ++kk) {
            aHi[kk] = *reinterpret_cast<const h8*>(ap + kk * 32);
            aLo[kk] = *reinterpret_cast<const h8*>(ap + D + kk * 32);
        }
    } else {
#pragma unroll
        for (int kk = 0; kk < 4; ++kk) {
            aHi[kk] = h8{0,0,0,0,0,0,0,0};
            aLo[kk] = h8{0,0,0,0,0,0,0,0};
        }
    }

    const char* wl = (const char*)wlds;
    int drow_base = row0 + (l4 << 2);

#pragma unroll
    for (int nt = 0; nt < 16; ++nt) {
        f32x4 a = f32x4{0.f, 0.f, 0.f, 0.f};
#pragma unroll
        for (int kk = 0; kk < 4; ++kk) {
            int fb = ((nt << 2) | kk) << 10;   // frag * 1024 B
            h8 bW = *reinterpret_cast<const h8*>(wl + fb + (lane << 4));
            a = __builtin_amdgcn_mfma_f32_16x16x32_f16(aHi[kk], bW, a, 0, 0, 0);
            a = __builtin_amdgcn_mfma_f32_16x16x32_f16(aLo[kk], bW, a, 0, 0, 0);
        }
        int col = (nt << 4) + l15;
        float bias = b1[col];
#pragma unroll
        for (int r = 0; r < 4; ++r) {
            int drow = drow_base + r;
            if (drow < N) {
                float v = a[r] + bias;
                v = v > 0.f ? v : 0.f;
                unsigned short hi = f2h_bits(v);
                unsigned short lo = f2h_bits(v - h2f(hi));
                unsigned int pv = (unsigned int)hi | ((unsigned int)lo << 16);
                if (col < 128) hidA[(size_t)drow * 128 + col] = pv;
                else           hidB[(size_t)drow * 128 + col - 128] = pv;
            }
        }
    }
}

// ---------------------------------------------------------------------------
// M2: GEMM2 + bias + BN stats. W2 (64 KB f16) in LDS. 2-term MFMA.
// ---------------------------------------------------------------------------
__global__ __launch_bounds__(1024) void k_m2(
    const unsigned int* hidA,                  // aliases aggp
    const unsigned int* hidB,                  // aliases hbuf
    float* h2,                                 // = hbuf
    const unsigned short* __restrict__ W2p,    // layer slice
    const float* __restrict__ b2,
    float* __restrict__ stats, int N)
{
    __shared__ uint4 wlds[4096];               // 64 KB
    __shared__ float s_sum[D], s_sq[D];
    int t = threadIdx.x;
    {
        const uint4* src = (const uint4*)W2p;
        for (int i = t; i < 4096; i += 1024) wlds[i] = src[i];
    }
    if (t < D) { s_sum[t] = 0.f; s_sq[t] = 0.f; }
    __syncthreads();

    int w = t >> 6, lane = t & 63;
    int l15 = lane & 15, l4 = lane >> 4;
    int tile = blockIdx.x * 16 + w;
    int row0 = tile * 16;
    bool active = row0 < N;

    if (active) {
        int arow = row0 + l15;
        const char* wl = (const char*)wlds;
        f32x4 acc2[8];
#pragma unroll
        for (int nt = 0; nt < 8; ++nt) acc2[nt] = f32x4{0.f, 0.f, 0.f, 0.f};

#pragma unroll
        for (int kk = 0; kk < 8; ++kk) {
            uint4 w0, w1;
            if (arow < N) {
                const unsigned int* base = (kk < 4)
                    ? (hidA + (size_t)arow * 128 + kk * 32 + l4 * 8)
                    : (hidB + (size_t)arow * 128 + (kk - 4) * 32 + l4 * 8);
                w0 = *reinterpret_cast<const uint4*>(base);
                w1 = *reinterpret_cast<const uint4*>(base + 4);
            } else {
                w0 = uint4{0,0,0,0}; w1 = uint4{0,0,0,0};
            }
            union { unsigned short u[8]; h8 v; } hA, lA;
            hA.u[0] = (unsigned short)(w0.x & 0xffffu); lA.u[0] = (unsigned short)(w0.x >> 16);
            hA.u[1] = (unsigned short)(w0.y & 0xffffu); lA.u[1] = (unsigned short)(w0.y >> 16);
            hA.u[2] = (unsigned short)(w0.z & 0xffffu); lA.u[2] = (unsigned short)(w0.z >> 16);
            hA.u[3] = (unsigned short)(w0.w & 0xffffu); lA.u[3] = (unsigned short)(w0.w >> 16);
            hA.u[4] = (unsigned short)(w1.x & 0xffffu); lA.u[4] = (unsigned short)(w1.x >> 16);
            hA.u[5] = (unsigned short)(w1.y & 0xffffu); lA.u[5] = (unsigned short)(w1.y >> 16);
            hA.u[6] = (unsigned short)(w1.z & 0xffffu); lA.u[6] = (unsigned short)(w1.z >> 16);
            hA.u[7] = (unsigned short)(w1.w & 0xffffu); lA.u[7] = (unsigned short)(w1.w >> 16);
#pragma unroll
            for (int nt = 0; nt < 8; ++nt) {
                int fb = ((nt << 3) | kk) << 10;
                h8 bW = *reinterpret_cast<const h8*>(wl + fb + (lane << 4));
                acc2[nt] = __builtin_amdgcn_mfma_f32_16x16x32_f16(hA.v, bW, acc2[nt], 0, 0, 0);
                acc2[nt] = __builtin_amdgcn_mfma_f32_16x16x32_f16(lA.v, bW, acc2[nt], 0, 0, 0);
            }
        }

        int drow_base = row0 + (l4 << 2);
#pragma unroll
        for (int nt = 0; nt < 8; ++nt) {
            int col = (nt << 4) + l15;
            float bias = b2[col];
            float cs = 0.f, cq = 0.f;
#pragma unroll
            for (int r = 0; r < 4; ++r) {
                int drow = drow_base + r;
                if (drow < N) {
                    float v = acc2[nt][r] + bias;
                    h2[(size_t)drow * 128 + col] = v;
                    cs += v; cq += v * v;
                }
            }
            atomicAdd(&s_sum[col], cs);
            atomicAdd(&s_sq[col],  cq);
        }
    }
    __syncthreads();
    if (t < D) {
        atomicAdd(stats + t,     s_sum[t]);
        atomicAdd(stats + D + t, s_sq[t]);
    }
}

// ---------------------------------------------------------------------------
// BN prep: scale/shift from sums
// ---------------------------------------------------------------------------
__global__ __launch_bounds__(128) void k_bnprep(
    const float* __restrict__ stats,
    const float* __restrict__ gamma, const float* __restrict__ beta,
    float* __restrict__ ss, float inv_n)
{
    int d = threadIdx.x;
    float mu  = stats[d] * inv_n;
    float var = stats[D + d] * inv_n - mu * mu;
    float sc  = rsqrtf(var + BN_EPS) * gamma[d];
    ss[d]     = sc;
    ss[D + d] = beta[d] - mu * sc;
}

// ---------------------------------------------------------------------------
// Final BN (no relu), in-place on d_out
// ---------------------------------------------------------------------------
__global__ __launch_bounds__(256) void k_bnfinal(
    float* __restrict__ h, const float* __restrict__ ss, int N)
{
    int idx = blockIdx.x * 256 + threadIdx.x;
    int row = idx >> 5;
    int d   = (idx & 31) * 4;
    if (row >= N) return;
    float4 v  = ldg4(h + (size_t)row * D + d);
    float4 sc = ldg4(ss + d);
    float4 sh = ldg4(ss + D + d);
    float4 o;
    o.x = fmaf(v.x, sc.x, sh.x);
    o.y = fmaf(v.y, sc.y, sh.y);
    o.z = fmaf(v.z, sc.z, sh.z);
    o.w = fmaf(v.w, sc.w, sh.w);
    *reinterpret_cast<float4*>(h + (size_t)row * D + d) = o;
}

// ---------------------------------------------------------------------------
static inline size_t align16(size_t x) { return (x + 15) & ~(size_t)15; }

extern "C" void kernel_launch(void* const* d_in, const int* in_sizes, int n_in,
                              void* d_out, int out_size, void* d_ws, size_t ws_size,
                              hipStream_t stream)
{
    const int*   x     = (const int*)  d_in[0];
    const int*   ei    = (const int*)  d_in[1];
    const int*   ea    = (const int*)  d_in[2];
    const float* ae1   = (const float*)d_in[3];
    const float* ae2   = (const float*)d_in[4];
    const float* be1   = (const float*)d_in[5];   // [5,7,128]
    const float* be2   = (const float*)d_in[6];   // [5,4,128]
    const float* W1    = (const float*)d_in[7];   // [5,128,256]
    const float* b1    = (const float*)d_in[8];   // [5,256]
    const float* W2    = (const float*)d_in[9];   // [5,256,128]
    const float* b2    = (const float*)d_in[10];  // [5,128]
    const float* gamma = (const float*)d_in[11];  // [5,128]
    const float* beta  = (const float*)d_in[12];  // [5,128]

    const int N = in_sizes[0] / 2;
    const int E = in_sizes[1] / 2;

    float* hbuf = (float*)d_out;

    // ---- workspace layout (bytes) ----
    char* wsb = (char*)d_ws;
    size_t o = 0;
    int* rowptr = (int*)(wsb + o);          o += align16((size_t)(N + 1) * 4);
    int* counts = (int*)(wsb + o);          o += align16((size_t)N * 9 * 4);
    float* stats = (float*)(wsb + o);       o += align16((size_t)5 * 2 * D * 4);
    const size_t zero_bytes = o;
    int* cursor = (int*)(wsb + o);          o += align16((size_t)N * 4);
    int* esrc = (int*)(wsb + o);            o += align16((size_t)E * 4);
    int* bsum = (int*)(wsb + o);            o += align16(1024 * 4);
    int* boff = (int*)(wsb + o);            o += align16(1024 * 4);
    float* ss = (float*)(wsb + o);          o += align16((size_t)5 * 2 * D * 4);
    float* bec = (float*)(wsb + o);         o += align16((size_t)5 * 10 * D * 4);
    unsigned short* W1p = (unsigned short*)(wsb + o); o += align16((size_t)5 * 32768 * 2);
    unsigned short* W2p = (unsigned short*)(wsb + o); o += align16((size_t)5 * 32768 * 2);
    unsigned short* aggp = (unsigned short*)(wsb + o); o += align16((size_t)N * 256 * 2);

    hipMemsetAsync(wsb, 0, zero_bytes, stream);

    const dim3 blk(256);
    const int nb_nodes  = (N * 32 + 255) / 256;
    const int nb_edges  = (E + 255) / 256;
    const int nchunks   = (N + 1023) / 1024;
    const int nb_gather = (N + 7) / 8;
    const int ntiles    = (N + 15) / 16;
    const int nb_m      = (ntiles + 15) / 16;   // 16 waves/block
    const float inv_n   = 1.0f / (float)N;

    unsigned int* hidA = (unsigned int*)aggp;
    unsigned int* hidB = (unsigned int*)hbuf;

    k_atom<<<nb_nodes, blk, 0, stream>>>(x, ae1, ae2, hbuf, N);
    k_hist<<<nb_edges, blk, 0, stream>>>(ei, ea, counts, E);
    k_scan1<<<nchunks, 1024, 0, stream>>>(counts, rowptr, cursor, bsum, N);
    k_scan2<<<1, 64, 0, stream>>>(bsum, boff, nchunks);
    k_scan3<<<nchunks, 1024, 0, stream>>>(rowptr, cursor, boff, N);
    k_fill<<<nb_edges, blk, 0, stream>>>(ei, cursor, esrc, E);
    k_bec<<<(5 * 10 * D + 255) / 256, blk, 0, stream>>>(be1, be2, bec);
    k_wconv<<<(2 * 5 * 4096 + 255) / 256, blk, 0, stream>>>(W1, W2, W1p, W2p);

    for (int l = 0; l < 5; ++l) {
        float* st = stats + (size_t)l * 2 * D;
        const float* becl = bec + (size_t)l * 10 * D;
        if (l == 0) {
            k_gather<0><<<nb_gather, blk, 0, stream>>>(
                hbuf, rowptr, esrc, counts, becl, nullptr, aggp, N);
        } else {
            k_gather<1><<<nb_gather, blk, 0, stream>>>(
                hbuf, rowptr, esrc, counts, becl, ss + (size_t)(l - 1) * 2 * D, aggp, N);
        }
        k_m1<<<nb_m, 1024, 0, stream>>>(
            aggp, hidA, hidB,
            W1p + (size_t)l * 32768, b1 + (size_t)l * HD, N);
        k_m2<<<nb_m, 1024, 0, stream>>>(
            hidA, hidB, hbuf,
            W2p + (size_t)l * 32768, b2 + (size_t)l * D, st, N);
        k_bnprep<<<1, 128, 0, stream>>>(st, gamma + (size_t)l * D,
                                        beta + (size_t)l * D,
                                        ss + (size_t)l * 2 * D, inv_n);
    }
    k_bnfinal<<<nb_nodes, blk, 0, stream>>>(hbuf, ss + (size_t)4 * 2 * D, N);
}

// Round 10
// 649.277 us; speedup vs baseline: 1.3464x; 1.1044x over previous
//
#include <hip/hip_runtime.h>

#define D 128
#define HD 256
#define BN_EPS 1e-5f

typedef __attribute__((ext_vector_type(8))) _Float16 h8;
typedef __attribute__((ext_vector_type(4))) float f32x4;

__device__ __forceinline__ float4 ldg4(const float* p) {
    return *reinterpret_cast<const float4*>(p);
}
// f32 <-> f16 bit helpers (RNE)
__device__ __forceinline__ unsigned short f2h_bits(float f) {
    union { _Float16 h; unsigned short u; } c; c.h = (_Float16)f; return c.u;
}
__device__ __forceinline__ float h2f(unsigned short b) {
    union { unsigned short u; _Float16 h; } c; c.u = b; return (float)c.h;
}

// ---------------------------------------------------------------------------
// K0: AtomEncoder -> f16 h  (hf[i] = f16(ae1[x0] + ae2[x1]))
// ---------------------------------------------------------------------------
__global__ __launch_bounds__(256) void k_atom(
    const int* __restrict__ x,
    const float* __restrict__ ae1, const float* __restrict__ ae2,
    unsigned short* __restrict__ hf, int N)
{
    int idx = blockIdx.x * 256 + threadIdx.x;
    int row = idx >> 5;
    int d   = (idx & 31) * 4;
    if (row >= N) return;
    int i0 = x[row * 2 + 0];
    int i1 = x[row * 2 + 1];
    float4 a = ldg4(ae1 + (size_t)i0 * D + d);
    float4 b = ldg4(ae2 + (size_t)i1 * D + d);
    ushort4 o = {f2h_bits(a.x + b.x), f2h_bits(a.y + b.y),
                 f2h_bits(a.z + b.z), f2h_bits(a.w + b.w)};
    *reinterpret_cast<ushort4*>(hf + (size_t)row * D + d) = o;
}

// ---------------------------------------------------------------------------
// CSR build 1: ONE atomic per edge (counts only; degree derived in scan1)
// ---------------------------------------------------------------------------
__global__ __launch_bounds__(256) void k_hist(
    const int* __restrict__ ei, const int* __restrict__ ea,
    int* __restrict__ counts, int E)
{
    int e = blockIdx.x * 256 + threadIdx.x;
    if (e >= E) return;
    int dst = ei[E + e];
    int c = ea[2 * e] * 3 + ea[2 * e + 1];
    atomicAdd(&counts[dst * 9 + c], 1);
}

// ---------------------------------------------------------------------------
// CSR build 2a/2b/2c: multi-block prefix sum; deg(i) = sum of counts[i][0..9)
// ---------------------------------------------------------------------------
__global__ __launch_bounds__(1024) void k_scan1(
    const int* __restrict__ counts,
    int* __restrict__ rowptr, int* __restrict__ cursor,
    int* __restrict__ bsum, int N)
{
    __shared__ int wsum[16];
    int t = threadIdx.x, lane = t & 63, w = t >> 6;
    int i = blockIdx.x * 1024 + t;
    int v = 0;
    if (i < N) {
        const int* cp = counts + (size_t)i * 9;
#pragma unroll
        for (int j = 0; j < 9; ++j) v += cp[j];
    }
    int incl = v;
#pragma unroll
    for (int off = 1; off < 64; off <<= 1) {
        int y = __shfl_up(incl, off);
        if (lane >= off) incl += y;
    }
    if (lane == 63) wsum[w] = incl;
    __syncthreads();
    if (t < 16) {
        int xv = wsum[t];
#pragma unroll
        for (int off = 1; off < 16; off <<= 1) {
            int y = __shfl_up(xv, off);
            if (t >= off) xv += y;
        }
        wsum[t] = xv;
    }
    __syncthreads();
    int woff = w ? wsum[w - 1] : 0;
    int full = woff + incl;
    if (i < N) { rowptr[i + 1] = full; cursor[i] = full - v; }
    if (t == 1023) bsum[blockIdx.x] = full;
}

__global__ __launch_bounds__(64) void k_scan2(
    const int* __restrict__ bsum, int* __restrict__ boff, int nchunks)
{
    int t = threadIdx.x;
    int carry = 0;
    for (int base = 0; base < nchunks; base += 64) {
        int idx = base + t;
        int v = (idx < nchunks) ? bsum[idx] : 0;
        int incl = v;
#pragma unroll
        for (int off = 1; off < 64; off <<= 1) {
            int y = __shfl_up(incl, off);
            if (t >= off) incl += y;
        }
        if (idx < nchunks) boff[idx] = carry + incl - v;
        carry += __shfl(incl, 63);
    }
}

__global__ __launch_bounds__(1024) void k_scan3(
    int* __restrict__ rowptr, int* __restrict__ cursor,
    const int* __restrict__ boff, int N)
{
    int t = threadIdx.x;
    int i = blockIdx.x * 1024 + t;
    int off = boff[blockIdx.x];
    if (i < N) { rowptr[i + 1] += off; cursor[i] += off; }
    if (blockIdx.x == 0 && t == 0) rowptr[0] = 0;
}

// ---------------------------------------------------------------------------
// CSR build 3: fill edge sources in CSR order
// ---------------------------------------------------------------------------
__global__ __launch_bounds__(256) void k_fill(
    const int* __restrict__ ei, int* __restrict__ cursor,
    int* __restrict__ esrc, int E)
{
    int e = blockIdx.x * 256 + threadIdx.x;
    if (e >= E) return;
    int dst = ei[E + e];
    int pos = atomicAdd(&cursor[dst], 1);
    esrc[pos] = ei[e];
}

// ---------------------------------------------------------------------------
// bec precompute
// ---------------------------------------------------------------------------
__global__ __launch_bounds__(256) void k_bec(
    const float* __restrict__ be1, const float* __restrict__ be2,
    float* __restrict__ bec)
{
    int idx = blockIdx.x * 256 + threadIdx.x;
    if (idx >= 5 * 10 * D) return;
    int d  = idx & (D - 1);
    int lc = idx >> 7;
    int l = lc / 10, c = lc % 10;
    int a0 = (c == 9) ? 6 : (c / 3);
    int a1 = (c == 9) ? 3 : (c % 3);
    bec[idx] = be1[((size_t)l * 7 + a0) * D + d] + be2[((size_t)l * 4 + a1) * D + d];
}

// ---------------------------------------------------------------------------
// Weight pack: single f16 per element, fragment-ordered for LDS staging.
// Per frag f: 64 lanes x 16B (h8) = 1024 B. 64 frags/layer = 64 KB.
// ---------------------------------------------------------------------------
__global__ __launch_bounds__(256) void k_wconv(
    const float* __restrict__ W1, const float* __restrict__ W2,
    unsigned short* __restrict__ W1p, unsigned short* __restrict__ W2p)
{
    int tid = blockIdx.x * 256 + threadIdx.x;
    if (tid >= 2 * 5 * 4096) return;
    bool isW2 = tid >= 5 * 4096;
    int r  = tid & 4095;
    int l  = (tid % (5 * 4096)) >> 12;
    int f  = r >> 6;
    int lane = r & 63;
    int l15 = lane & 15, l4 = lane >> 4;
    if (!isW2) {
        int nt = f >> 2, kk = f & 3;
        int n = nt * 16 + l15;
        int kbase = kk * 32 + l4 * 8;
        const float* src = W1 + ((size_t)l * D + kbase) * HD + n;
        unsigned short* out = W1p + (size_t)l * 32768 + (size_t)f * 512 + lane * 8;
#pragma unroll
        for (int j = 0; j < 8; ++j) out[j] = f2h_bits(src[(size_t)j * HD]);
    } else {
        int nt = f >> 3, kk = f & 7;
        int n = nt * 16 + l15;
        int kbase = kk * 32 + l4 * 8;
        const float* src = W2 + ((size_t)l * HD + kbase) * D + n;
        unsigned short* out = W2p + (size_t)l * 32768 + (size_t)f * 512 + lane * 8;
#pragma unroll
        for (int j = 0; j < 8; ++j) out[j] = f2h_bits(src[(size_t)j * D]);
    }
}

// ---------------------------------------------------------------------------
// Gather from f16 h (+ fused BN affine + relu of previous layer),
// emits f16 hi/lo agg. aggp row: 256 ushorts = [128 hi][128 lo].
// ---------------------------------------------------------------------------
template <int AFFINE>
__global__ __launch_bounds__(256) void k_gather(
    const unsigned short* __restrict__ hf, const int* __restrict__ rowptr,
    const int* __restrict__ esrc, const int* __restrict__ counts,
    const float* __restrict__ bec,
    const float* __restrict__ ss,
    unsigned short* __restrict__ aggp, int N)
{
    int g = threadIdx.x >> 5;
    int lane = threadIdx.x & 31;
    int d = lane * 4;
    int node = blockIdx.x * 8 + g;
    if (node >= N) return;

    float4 sc, sh;
    if (AFFINE) { sc = ldg4(ss + d); sh = ldg4(ss + D + d); }

    ushort4 u = *reinterpret_cast<const ushort4*>(hf + (size_t)node * D + d);
    float4 acc = {h2f(u.x), h2f(u.y), h2f(u.z), h2f(u.w)};
    if (AFFINE) {
        acc.x = fmaf(acc.x, sc.x, sh.x); acc.y = fmaf(acc.y, sc.y, sh.y);
        acc.z = fmaf(acc.z, sc.z, sh.z); acc.w = fmaf(acc.w, sc.w, sh.w);
        acc.x = acc.x > 0.f ? acc.x : 0.f; acc.y = acc.y > 0.f ? acc.y : 0.f;
        acc.z = acc.z > 0.f ? acc.z : 0.f; acc.w = acc.w > 0.f ? acc.w : 0.f;
    }
    float4 sl = ldg4(bec + 9 * D + d);
    acc.x += sl.x; acc.y += sl.y; acc.z += sl.z; acc.w += sl.w;

#pragma unroll
    for (int c = 0; c < 9; ++c) {
        float fc = (float)counts[node * 9 + c];
        float4 b = ldg4(bec + c * D + d);
        acc.x = fmaf(fc, b.x, acc.x);
        acc.y = fmaf(fc, b.y, acc.y);
        acc.z = fmaf(fc, b.z, acc.z);
        acc.w = fmaf(fc, b.w, acc.w);
    }

    int beg = rowptr[node], end = rowptr[node + 1];
    int e = beg;
    for (; e + 3 < end; e += 4) {
        int s0 = esrc[e], s1 = esrc[e + 1], s2 = esrc[e + 2], s3 = esrc[e + 3];
        ushort4 u0 = *reinterpret_cast<const ushort4*>(hf + (size_t)s0 * D + d);
        ushort4 u1 = *reinterpret_cast<const ushort4*>(hf + (size_t)s1 * D + d);
        ushort4 u2 = *reinterpret_cast<const ushort4*>(hf + (size_t)s2 * D + d);
        ushort4 u3 = *reinterpret_cast<const ushort4*>(hf + (size_t)s3 * D + d);
        float4 h0 = {h2f(u0.x), h2f(u0.y), h2f(u0.z), h2f(u0.w)};
        float4 h1 = {h2f(u1.x), h2f(u1.y), h2f(u1.z), h2f(u1.w)};
        float4 h2 = {h2f(u2.x), h2f(u2.y), h2f(u2.z), h2f(u2.w)};
        float4 h3 = {h2f(u3.x), h2f(u3.y), h2f(u3.z), h2f(u3.w)};
        if (AFFINE) {
            h0.x = fmaf(h0.x, sc.x, sh.x); h0.y = fmaf(h0.y, sc.y, sh.y);
            h0.z = fmaf(h0.z, sc.z, sh.z); h0.w = fmaf(h0.w, sc.w, sh.w);
            h1.x = fmaf(h1.x, sc.x, sh.x); h1.y = fmaf(h1.y, sc.y, sh.y);
            h1.z = fmaf(h1.z, sc.z, sh.z); h1.w = fmaf(h1.w, sc.w, sh.w);
            h2.x = fmaf(h2.x, sc.x, sh.x); h2.y = fmaf(h2.y, sc.y, sh.y);
            h2.z = fmaf(h2.z, sc.z, sh.z); h2.w = fmaf(h2.w, sc.w, sh.w);
            h3.x = fmaf(h3.x, sc.x, sh.x); h3.y = fmaf(h3.y, sc.y, sh.y);
            h3.z = fmaf(h3.z, sc.z, sh.z); h3.w = fmaf(h3.w, sc.w, sh.w);
            h0.x = h0.x > 0.f ? h0.x : 0.f; h0.y = h0.y > 0.f ? h0.y : 0.f;
            h0.z = h0.z > 0.f ? h0.z : 0.f; h0.w = h0.w > 0.f ? h0.w : 0.f;
            h1.x = h1.x > 0.f ? h1.x : 0.f; h1.y = h1.y > 0.f ? h1.y : 0.f;
            h1.z = h1.z > 0.f ? h1.z : 0.f; h1.w = h1.w > 0.f ? h1.w : 0.f;
            h2.x = h2.x > 0.f ? h2.x : 0.f; h2.y = h2.y > 0.f ? h2.y : 0.f;
            h2.z = h2.z > 0.f ? h2.z : 0.f; h2.w = h2.w > 0.f ? h2.w : 0.f;
            h3.x = h3.x > 0.f ? h3.x : 0.f; h3.y = h3.y > 0.f ? h3.y : 0.f;
            h3.z = h3.z > 0.f ? h3.z : 0.f; h3.w = h3.w > 0.f ? h3.w : 0.f;
        }
        acc.x += (h0.x + h1.x) + (h2.x + h3.x);
        acc.y += (h0.y + h1.y) + (h2.y + h3.y);
        acc.z += (h0.z + h1.z) + (h2.z + h3.z);
        acc.w += (h0.w + h1.w) + (h2.w + h3.w);
    }
    for (; e < end; ++e) {
        ushort4 u0 = *reinterpret_cast<const ushort4*>(hf + (size_t)esrc[e] * D + d);
        float4 h0 = {h2f(u0.x), h2f(u0.y), h2f(u0.z), h2f(u0.w)};
        if (AFFINE) {
            h0.x = fmaf(h0.x, sc.x, sh.x); h0.y = fmaf(h0.y, sc.y, sh.y);
            h0.z = fmaf(h0.z, sc.z, sh.z); h0.w = fmaf(h0.w, sc.w, sh.w);
            h0.x = h0.x > 0.f ? h0.x : 0.f; h0.y = h0.y > 0.f ? h0.y : 0.f;
            h0.z = h0.z > 0.f ? h0.z : 0.f; h0.w = h0.w > 0.f ? h0.w : 0.f;
        }
        acc.x += h0.x; acc.y += h0.y; acc.z += h0.z; acc.w += h0.w;
    }

    unsigned short q0 = f2h_bits(acc.x), q1 = f2h_bits(acc.y),
                   q2 = f2h_bits(acc.z), q3 = f2h_bits(acc.w);
    ushort4 hv = {q0, q1, q2, q3};
    ushort4 lv = {f2h_bits(acc.x - h2f(q0)), f2h_bits(acc.y - h2f(q1)),
                  f2h_bits(acc.z - h2f(q2)), f2h_bits(acc.w - h2f(q3))};
    unsigned short* op = aggp + (size_t)node * 256;
    *reinterpret_cast<ushort4*>(op + d) = hv;
    *reinterpret_cast<ushort4*>(op + D + d) = lv;
}

// ---------------------------------------------------------------------------
// M1: GEMM1 + bias + relu + f16-split. W1 (64 KB f16) staged in LDS.
// 2-term MFMA: aHi*W + aLo*W. 1024 thr = 16 waves, wave tile = 16 rows.
// Hidden (u32 hi|lo) overwrites aggp (cols 0..127) and hbuf (cols 128..255).
// ---------------------------------------------------------------------------
__global__ __launch_bounds__(1024) void k_m1(
    const unsigned short* __restrict__ aggp,   // [N][256] hi|lo (read)
    unsigned int* hidA,                        // aliases aggp (write)
    unsigned int* hidB,                        // aliases hbuf (write)
    const unsigned short* __restrict__ W1p,    // layer slice, 32768 ushorts
    const float* __restrict__ b1, int N)
{
    __shared__ uint4 wlds[4096];               // 64 KB
    int t = threadIdx.x;
    {
        const uint4* src = (const uint4*)W1p;
        for (int i = t; i < 4096; i += 1024) wlds[i] = src[i];
    }
    __syncthreads();                           // no barriers after this

    int w = t >> 6, lane = t & 63;
    int l15 = lane & 15, l4 = lane >> 4;
    int tile = blockIdx.x * 16 + w;
    int row0 = tile * 16;
    if (row0 >= N) return;

    int arow = row0 + l15;
    h8 aHi[4], aLo[4];
    if (arow < N) {
        const unsigned short* ap = aggp + (size_t)arow * 256 + l4 * 8;
#pragma unroll
        for (int kk = 0; kk < 4; ++kk) {
            aHi[kk] = *reinterpret_cast<const h8*>(ap + kk * 32);
            aLo[kk] = *reinterpret_cast<const h8*>(ap + D + kk * 32);
        }
    } else {
#pragma unroll
        for (int kk = 0; kk < 4; ++kk) {
            aHi[kk] = h8{0,0,0,0,0,0,0,0};
            aLo[kk] = h8{0,0,0,0,0,0,0,0};
        }
    }

    const char* wl = (const char*)wlds;
    int drow_base = row0 + (l4 << 2);

#pragma unroll
    for (int nt = 0; nt < 16; ++nt) {
        f32x4 a = f32x4{0.f, 0.f, 0.f, 0.f};
#pragma unroll
        for (int kk = 0; kk < 4; ++kk) {
            int fb = ((nt << 2) | kk) << 10;   // frag * 1024 B
            h8 bW = *reinterpret_cast<const h8*>(wl + fb + (lane << 4));
            a = __builtin_amdgcn_mfma_f32_16x16x32_f16(aHi[kk], bW, a, 0, 0, 0);
            a = __builtin_amdgcn_mfma_f32_16x16x32_f16(aLo[kk], bW, a, 0, 0, 0);
        }
        int col = (nt << 4) + l15;
        float bias = b1[col];
#pragma unroll
        for (int r = 0; r < 4; ++r) {
            int drow = drow_base + r;
            if (drow < N) {
                float v = a[r] + bias;
                v = v > 0.f ? v : 0.f;
                unsigned short hi = f2h_bits(v);
                unsigned short lo = f2h_bits(v - h2f(hi));
                unsigned int pv = (unsigned int)hi | ((unsigned int)lo << 16);
                if (col < 128) hidA[(size_t)drow * 128 + col] = pv;
                else           hidB[(size_t)drow * 128 + col - 128] = pv;
            }
        }
    }
}

// ---------------------------------------------------------------------------
// M2: GEMM2 + bias + BN stats. W2 (64 KB f16) in LDS. 2-term MFMA.
// Writes f16 h (for next gather) always; fp32 h2 only in last layer.
// ---------------------------------------------------------------------------
template <int LAST>
__global__ __launch_bounds__(1024) void k_m2(
    const unsigned int* hidA,                  // aliases aggp
    const unsigned int* hidB,                  // aliases hbuf
    unsigned short* __restrict__ hf,           // f16 h out
    float* h2,                                 // = hbuf (LAST only)
    const unsigned short* __restrict__ W2p,    // layer slice
    const float* __restrict__ b2,
    float* __restrict__ stats, int N)
{
    __shared__ uint4 wlds[4096];               // 64 KB
    __shared__ float s_sum[D], s_sq[D];
    int t = threadIdx.x;
    {
        const uint4* src = (const uint4*)W2p;
        for (int i = t; i < 4096; i += 1024) wlds[i] = src[i];
    }
    if (t < D) { s_sum[t] = 0.f; s_sq[t] = 0.f; }
    __syncthreads();

    int w = t >> 6, lane = t & 63;
    int l15 = lane & 15, l4 = lane >> 4;
    int tile = blockIdx.x * 16 + w;
    int row0 = tile * 16;
    bool active = row0 < N;

    if (active) {
        int arow = row0 + l15;
        const char* wl = (const char*)wlds;
        f32x4 acc2[8];
#pragma unroll
        for (int nt = 0; nt < 8; ++nt) acc2[nt] = f32x4{0.f, 0.f, 0.f, 0.f};

#pragma unroll
        for (int kk = 0; kk < 8; ++kk) {
            uint4 w0, w1;
            if (arow < N) {
                const unsigned int* base = (kk < 4)
                    ? (hidA + (size_t)arow * 128 + kk * 32 + l4 * 8)
                    : (hidB + (size_t)arow * 128 + (kk - 4) * 32 + l4 * 8);
                w0 = *reinterpret_cast<const uint4*>(base);
                w1 = *reinterpret_cast<const uint4*>(base + 4);
            } else {
                w0 = uint4{0,0,0,0}; w1 = uint4{0,0,0,0};
            }
            union { unsigned short u[8]; h8 v; } hA, lA;
            hA.u[0] = (unsigned short)(w0.x & 0xffffu); lA.u[0] = (unsigned short)(w0.x >> 16);
            hA.u[1] = (unsigned short)(w0.y & 0xffffu); lA.u[1] = (unsigned short)(w0.y >> 16);
            hA.u[2] = (unsigned short)(w0.z & 0xffffu); lA.u[2] = (unsigned short)(w0.z >> 16);
            hA.u[3] = (unsigned short)(w0.w & 0xffffu); lA.u[3] = (unsigned short)(w0.w >> 16);
            hA.u[4] = (unsigned short)(w1.x & 0xffffu); lA.u[4] = (unsigned short)(w1.x >> 16);
            hA.u[5] = (unsigned short)(w1.y & 0xffffu); lA.u[5] = (unsigned short)(w1.y >> 16);
            hA.u[6] = (unsigned short)(w1.z & 0xffffu); lA.u[6] = (unsigned short)(w1.z >> 16);
            hA.u[7] = (unsigned short)(w1.w & 0xffffu); lA.u[7] = (unsigned short)(w1.w >> 16);
#pragma unroll
            for (int nt = 0; nt < 8; ++nt) {
                int fb = ((nt << 3) | kk) << 10;
                h8 bW = *reinterpret_cast<const h8*>(wl + fb + (lane << 4));
                acc2[nt] = __builtin_amdgcn_mfma_f32_16x16x32_f16(hA.v, bW, acc2[nt], 0, 0, 0);
                acc2[nt] = __builtin_amdgcn_mfma_f32_16x16x32_f16(lA.v, bW, acc2[nt], 0, 0, 0);
            }
        }

        int drow_base = row0 + (l4 << 2);
#pragma unroll
        for (int nt = 0; nt < 8; ++nt) {
            int col = (nt << 4) + l15;
            float bias = b2[col];
            float cs = 0.f, cq = 0.f;
#pragma unroll
            for (int r = 0; r < 4; ++r) {
                int drow = drow_base + r;
                if (drow < N) {
                    float v = acc2[nt][r] + bias;
                    hf[(size_t)drow * D + col] = f2h_bits(v);
                    if (LAST) h2[(size_t)drow * D + col] = v;
                    cs += v; cq += v * v;
                }
            }
            atomicAdd(&s_sum[col], cs);
            atomicAdd(&s_sq[col],  cq);
        }
    }
    __syncthreads();
    if (t < D) {
        atomicAdd(stats + t,     s_sum[t]);
        atomicAdd(stats + D + t, s_sq[t]);
    }
}

// ---------------------------------------------------------------------------
// BN prep: scale/shift from sums
// ---------------------------------------------------------------------------
__global__ __launch_bounds__(128) void k_bnprep(
    const float* __restrict__ stats,
    const float* __restrict__ gamma, const float* __restrict__ beta,
    float* __restrict__ ss, float inv_n)
{
    int d = threadIdx.x;
    float mu  = stats[d] * inv_n;
    float var = stats[D + d] * inv_n - mu * mu;
    float sc  = rsqrtf(var + BN_EPS) * gamma[d];
    ss[d]     = sc;
    ss[D + d] = beta[d] - mu * sc;
}

// ---------------------------------------------------------------------------
// Final BN (no relu), in-place on d_out
// ---------------------------------------------------------------------------
__global__ __launch_bounds__(256) void k_bnfinal(
    float* __restrict__ h, const float* __restrict__ ss, int N)
{
    int idx = blockIdx.x * 256 + threadIdx.x;
    int row = idx >> 5;
    int d   = (idx & 31) * 4;
    if (row >= N) return;
    float4 v  = ldg4(h + (size_t)row * D + d);
    float4 sc = ldg4(ss + d);
    float4 sh = ldg4(ss + D + d);
    float4 o;
    o.x = fmaf(v.x, sc.x, sh.x);
    o.y = fmaf(v.y, sc.y, sh.y);
    o.z = fmaf(v.z, sc.z, sh.z);
    o.w = fmaf(v.w, sc.w, sh.w);
    *reinterpret_cast<float4*>(h + (size_t)row * D + d) = o;
}

// ---------------------------------------------------------------------------
static inline size_t align16(size_t x) { return (x + 15) & ~(size_t)15; }

extern "C" void kernel_launch(void* const* d_in, const int* in_sizes, int n_in,
                              void* d_out, int out_size, void* d_ws, size_t ws_size,
                              hipStream_t stream)
{
    const int*   x     = (const int*)  d_in[0];
    const int*   ei    = (const int*)  d_in[1];
    const int*   ea    = (const int*)  d_in[2];
    const float* ae1   = (const float*)d_in[3];
    const float* ae2   = (const float*)d_in[4];
    const float* be1   = (const float*)d_in[5];   // [5,7,128]
    const float* be2   = (const float*)d_in[6];   // [5,4,128]
    const float* W1    = (const float*)d_in[7];   // [5,128,256]
    const float* b1    = (const float*)d_in[8];   // [5,256]
    const float* W2    = (const float*)d_in[9];   // [5,256,128]
    const float* b2    = (const float*)d_in[10];  // [5,128]
    const float* gamma = (const float*)d_in[11];  // [5,128]
    const float* beta  = (const float*)d_in[12];  // [5,128]

    const int N = in_sizes[0] / 2;
    const int E = in_sizes[1] / 2;

    float* hbuf = (float*)d_out;

    // ---- workspace layout (bytes) ----
    char* wsb = (char*)d_ws;
    size_t o = 0;
    int* rowptr = (int*)(wsb + o);          o += align16((size_t)(N + 1) * 4);
    int* counts = (int*)(wsb + o);          o += align16((size_t)N * 9 * 4);
    float* stats = (float*)(wsb + o);       o += align16((size_t)5 * 2 * D * 4);
    const size_t zero_bytes = o;
    int* cursor = (int*)(wsb + o);          o += align16((size_t)N * 4);
    int* esrc = (int*)(wsb + o);            o += align16((size_t)E * 4);
    int* bsum = (int*)(wsb + o);            o += align16(1024 * 4);
    int* boff = (int*)(wsb + o);            o += align16(1024 * 4);
    float* ss = (float*)(wsb + o);          o += align16((size_t)5 * 2 * D * 4);
    float* bec = (float*)(wsb + o);         o += align16((size_t)5 * 10 * D * 4);
    unsigned short* W1p = (unsigned short*)(wsb + o); o += align16((size_t)5 * 32768 * 2);
    unsigned short* W2p = (unsigned short*)(wsb + o); o += align16((size_t)5 * 32768 * 2);
    unsigned short* aggp = (unsigned short*)(wsb + o); o += align16((size_t)N * 256 * 2);
    unsigned short* hf16 = (unsigned short*)(wsb + o); o += align16((size_t)N * D * 2);

    hipMemsetAsync(wsb, 0, zero_bytes, stream);

    const dim3 blk(256);
    const int nb_nodes  = (N * 32 + 255) / 256;
    const int nb_edges  = (E + 255) / 256;
    const int nchunks   = (N + 1023) / 1024;
    const int nb_gather = (N + 7) / 8;
    const int ntiles    = (N + 15) / 16;
    const int nb_m      = (ntiles + 15) / 16;   // 16 waves/block
    const float inv_n   = 1.0f / (float)N;

    unsigned int* hidA = (unsigned int*)aggp;
    unsigned int* hidB = (unsigned int*)hbuf;

    k_atom<<<nb_nodes, blk, 0, stream>>>(x, ae1, ae2, hf16, N);
    k_hist<<<nb_edges, blk, 0, stream>>>(ei, ea, counts, E);
    k_scan1<<<nchunks, 1024, 0, stream>>>(counts, rowptr, cursor, bsum, N);
    k_scan2<<<1, 64, 0, stream>>>(bsum, boff, nchunks);
    k_scan3<<<nchunks, 1024, 0, stream>>>(rowptr, cursor, boff, N);
    k_fill<<<nb_edges, blk, 0, stream>>>(ei, cursor, esrc, E);
    k_bec<<<(5 * 10 * D + 255) / 256, blk, 0, stream>>>(be1, be2, bec);
    k_wconv<<<(2 * 5 * 4096 + 255) / 256, blk, 0, stream>>>(W1, W2, W1p, W2p);

    for (int l = 0; l < 5; ++l) {
        float* st = stats + (size_t)l * 2 * D;
        const float* becl = bec + (size_t)l * 10 * D;
        if (l == 0) {
            k_gather<0><<<nb_gather, blk, 0, stream>>>(
                hf16, rowptr, esrc, counts, becl, nullptr, aggp, N);
        } else {
            k_gather<1><<<nb_gather, blk, 0, stream>>>(
                hf16, rowptr, esrc, counts, becl, ss + (size_t)(l - 1) * 2 * D, aggp, N);
        }
        k_m1<<<nb_m, 1024, 0, stream>>>(
            aggp, hidA, hidB,
            W1p + (size_t)l * 32768, b1 + (size_t)l * HD, N);
        if (l < 4) {
            k_m2<0><<<nb_m, 1024, 0, stream>>>(
                hidA, hidB, hf16, hbuf,
                W2p + (size_t)l * 32768, b2 + (size_t)l * D, st, N);
        } else {
            k_m2<1><<<nb_m, 1024, 0, stream>>>(
                hidA, hidB, hf16, hbuf,
                W2p + (size_t)l * 32768, b2 + (size_t)l * D, st, N);
        }
        k_bnprep<<<1, 128, 0, stream>>>(st, gamma + (size_t)l * D,
                                        beta + (size_t)l * D,
                                        ss + (size_t)l * 2 * D, inv_n);
    }
    k_bnfinal<<<nb_nodes, blk, 0, stream>>>(hbuf, ss + (size_t)4 * 2 * D, N);
}